// Round 1
// baseline (309.901 us; speedup 1.0000x reference)
//
#include <hip/hip_runtime.h>
#include <hip/hip_bf16.h>

#define THREADS 256
#define BSHIFT 9              // 512 nodes per coarse bucket; NB = ceil(N/512) <= 256
#define BIN_CHUNK 4096        // edges per k_bin block (16/thread)

typedef __attribute__((ext_vector_type(8))) short bf16x8;
typedef __attribute__((ext_vector_type(4))) float f32x4;

// ---------------- helpers ----------------

__device__ inline unsigned short f2bf(float f) {  // round-to-nearest-even
    unsigned int u = __float_as_uint(f);
    unsigned int r = (u + 0x7fffu + ((u >> 16) & 1u)) >> 16;
    return (unsigned short)r;
}

__device__ inline unsigned int pack_bf2(float x, float y) {
    return (unsigned int)f2bf(x) | ((unsigned int)f2bf(y) << 16);
}

__device__ inline float2 bf2_to_f2(unsigned int u) {  // low bf16 -> x, high bf16 -> y
    float2 r;
    r.x = __uint_as_float(u << 16);
    r.y = __uint_as_float(u & 0xffff0000u);
    return r;
}

__device__ inline unsigned short bf_relu(unsigned short v) {
    return (v & 0x8000u) ? (unsigned short)0 : v;
}

// ---------------- CSR build: padded bucket windows, packed 4B edges ----------------
// Edge record: (dst_local:9 bits << 23) | src. bcur holds zero-based counts
// (memset to 0); absolute position = b*cap + count.

__global__ __launch_bounds__(256) void k_bin(const int* __restrict__ src,
                                             const int* __restrict__ dst,
                                             int* __restrict__ bcur,
                                             unsigned int* __restrict__ binned,
                                             int E, int NB, int cap) {
    __shared__ int bcnt[256];
    __shared__ int bres[256];
    int t = threadIdx.x;
    bcnt[t] = 0;
    __syncthreads();
    int base = blockIdx.x * BIN_CHUNK;
    int sv[16], dv[16];
#pragma unroll
    for (int i = 0; i < 16; ++i) {
        int e = base + t + i * 256;
        if (e < E) {
            sv[i] = src[e];
            dv[i] = dst[e];
            atomicAdd(&bcnt[dv[i] >> BSHIFT], 1);
        } else {
            dv[i] = -1;
        }
    }
    __syncthreads();
    if (t < NB) {
        int old = bcnt[t] ? atomicAdd(&bcur[t], bcnt[t]) : 0;
        bres[t] = t * cap + old;
    }
    __syncthreads();
#pragma unroll
    for (int i = 0; i < 16; ++i) {
        if (dv[i] >= 0) {
            int b = dv[i] >> BSHIFT;
            int pos = atomicAdd(&bres[b], 1);
            if (pos < (b + 1) * cap)  // overflow guard (statistically never trips)
                binned[pos] = ((unsigned int)(dv[i] & 511) << 23) | (unsigned int)sv[i];
        }
    }
}

// per-bucket: histogram -> intra-bucket scan -> rp/deg/dinv, then place srcs
// into eperm via LDS cursors. One block per bucket; window re-read is L2-hot.
__global__ __launch_bounds__(256) void k_node_place(const unsigned int* __restrict__ binned,
                                                    const int* __restrict__ bcur, int cap,
                                                    int* __restrict__ rp,
                                                    int* __restrict__ deg,
                                                    float* __restrict__ dinv,
                                                    int* __restrict__ eperm, int N) {
    __shared__ int lc[512];
    __shared__ int s[256];
    int b = blockIdx.x;
    int t = threadIdx.x;
    int beg = b * cap;
    int end = beg + min(bcur[b], cap);
    int d0 = b << BSHIFT;
    lc[t] = 0;
    lc[t + 256] = 0;
    __syncthreads();
    for (int j = beg + t; j < end; j += 256) atomicAdd(&lc[binned[j] >> 23], 1);
    __syncthreads();
    int a = lc[2 * t], c = lc[2 * t + 1];
    int pair = a + c;
    s[t] = pair;
    __syncthreads();
    for (int off = 1; off < 256; off <<= 1) {
        int add = (t >= off) ? s[t - off] : 0;
        __syncthreads();
        s[t] += add;
        __syncthreads();
    }
    int excl = s[t] - pair;
    int st0 = beg + excl, st1 = st0 + a;
    int node0 = d0 + 2 * t;
    if (node0 < N) {
        rp[node0] = st0;
        deg[node0] = a;
        dinv[node0] = rsqrtf((float)a + 1.0f);  // +1 = self-loop
    }
    if (node0 + 1 < N) {
        rp[node0 + 1] = st1;
        deg[node0 + 1] = c;
        dinv[node0 + 1] = rsqrtf((float)c + 1.0f);
    }
    __syncthreads();
    lc[2 * t] = st0;               // repurpose lc as placement cursors
    lc[2 * t + 1] = st1;
    __syncthreads();
    for (int j = beg + t; j < end; j += 256) {
        unsigned int p = binned[j];
        int pos = atomicAdd(&lc[p >> 23], 1);
        eperm[pos] = (int)(p & 0x7fffffu);
    }
}

// ---------------- MFMA GEMM: C[M x N](bf16) = dinv[row] * (A[M x 128] @ W[128 x N]) ----
// M-tile 64 (36 KB LDS -> 4 blocks/CU; staging is latency-bound and needs the
// occupancy — the 128-tile variant at 2 blocks/CU measured slower, R13).

template <int N, bool ABF16_RELU>
__global__ __launch_bounds__(256) void k_gemm_mfma(const void* __restrict__ Av,
                                                   const float* __restrict__ W,
                                                   const float* __restrict__ dinv,
                                                   unsigned short* __restrict__ C, int M) {
    static_assert(N == 64 || N == 128, "N must be 64 or 128");
    constexpr int NT = N / 64;
    constexpr int KP = 136;
    __shared__ short As[64 * KP];
    __shared__ short Bs[N * KP];
    __shared__ float sDin[64];

    const int t = threadIdx.x;
    const int m0 = blockIdx.x * 64;

    {
        int ar = t >> 5;
        int ac = (t & 31) * 4;
#pragma unroll
        for (int rb = 0; rb < 64; rb += 8) {
            int lrow = rb + ar;
            int row = m0 + lrow;
            ushort4 sv = make_ushort4(0, 0, 0, 0);
            if (ABF16_RELU) {
                if (row < M) {
                    ushort4 u = *(const ushort4*)((const unsigned short*)Av + (size_t)row * 128 + ac);
                    sv.x = bf_relu(u.x); sv.y = bf_relu(u.y);
                    sv.z = bf_relu(u.z); sv.w = bf_relu(u.w);
                }
            } else {
                if (row < M) {
                    float4 v = *(const float4*)((const float*)Av + (size_t)row * 128 + ac);
                    sv.x = f2bf(v.x); sv.y = f2bf(v.y); sv.z = f2bf(v.z); sv.w = f2bf(v.w);
                }
            }
            *(ushort4*)&As[lrow * KP + ac] = sv;
        }
    }
    {
        constexpr int TPR = N / 4;
        constexpr int KPI = 256 / TPR;
        int bk = t / TPR;
        int bn = (t % TPR) * 4;
#pragma unroll
        for (int kb = 0; kb < 128; kb += KPI) {
            int k = kb + bk;
            float4 wv = *(const float4*)(W + (size_t)k * N + bn);
            Bs[(bn + 0) * KP + k] = f2bf(wv.x);
            Bs[(bn + 1) * KP + k] = f2bf(wv.y);
            Bs[(bn + 2) * KP + k] = f2bf(wv.z);
            Bs[(bn + 3) * KP + k] = f2bf(wv.w);
        }
    }
    if (t < 64) sDin[t] = (m0 + t < M) ? dinv[m0 + t] : 1.0f;
    __syncthreads();

    const int w = t >> 6;
    const int lane = t & 63;
    const int lm = lane & 15;
    const int qd = lane >> 4;
    const int n0w = w * 16 * NT;

    f32x4 acc[4][NT];
#pragma unroll
    for (int mi = 0; mi < 4; ++mi)
#pragma unroll
        for (int ni = 0; ni < NT; ++ni) acc[mi][ni] = (f32x4){0.f, 0.f, 0.f, 0.f};

#pragma unroll
    for (int ks = 0; ks < 4; ++ks) {
        bf16x8 a[4], b[NT];
#pragma unroll
        for (int mi = 0; mi < 4; ++mi)
            a[mi] = *(const bf16x8*)&As[(mi * 16 + lm) * KP + ks * 32 + qd * 8];
#pragma unroll
        for (int ni = 0; ni < NT; ++ni)
            b[ni] = *(const bf16x8*)&Bs[(n0w + ni * 16 + lm) * KP + ks * 32 + qd * 8];
#pragma unroll
        for (int mi = 0; mi < 4; ++mi)
#pragma unroll
            for (int ni = 0; ni < NT; ++ni)
                acc[mi][ni] = __builtin_amdgcn_mfma_f32_16x16x32_bf16(a[mi], b[ni], acc[mi][ni], 0, 0, 0);
    }

#pragma unroll
    for (int mi = 0; mi < 4; ++mi) {
#pragma unroll
        for (int ni = 0; ni < NT; ++ni) {
            int col = n0w + ni * 16 + lm;
#pragma unroll
            for (int r = 0; r < 4; ++r) {
                int lrow = mi * 16 + qd * 4 + r;
                int row = m0 + lrow;
                if (row < M) C[(size_t)row * N + col] = f2bf(sDin[lrow] * acc[mi][ni][r]);
            }
        }
    }
}

// ---------------- CSR gather: out[d] = dinv[d] * (sum_in h'[src] + h'[d]) + b --------
// rp/deg addressing (padded windows are gapped). Unroll-16 + 8/4/2/1 ladder.

__global__ __launch_bounds__(256) void k_gather128(const int* __restrict__ rp,
                                                   const int* __restrict__ deg,
                                                   const int* __restrict__ eperm,
                                                   const float* __restrict__ dinv,
                                                   const unsigned int* __restrict__ h,  // bf16x2
                                                   const float* __restrict__ bias,
                                                   unsigned int* __restrict__ out,      // bf16x2
                                                   int n) {
    int node = blockIdx.x * 4 + (threadIdx.x >> 6);
    if (node >= n) return;
    int lane = threadIdx.x & 63;
    int beg = rp[node];
    int end = beg + deg[node];
    float2 acc = bf2_to_f2(h[(size_t)node * 64 + lane]);  // self h'[d]
    int j = beg;
    for (; j + 16 <= end; j += 16) {
        float2 a0 = make_float2(0.f, 0.f), a1 = a0;
#pragma unroll
        for (int u = 0; u < 2; ++u) {
            int e0 = eperm[j + 8 * u],     e1 = eperm[j + 8 * u + 1];
            int e2 = eperm[j + 8 * u + 2], e3 = eperm[j + 8 * u + 3];
            int e4 = eperm[j + 8 * u + 4], e5 = eperm[j + 8 * u + 5];
            int e6 = eperm[j + 8 * u + 6], e7 = eperm[j + 8 * u + 7];
            float2 v0 = bf2_to_f2(h[(size_t)e0 * 64 + lane]);
            float2 v1 = bf2_to_f2(h[(size_t)e1 * 64 + lane]);
            float2 v2 = bf2_to_f2(h[(size_t)e2 * 64 + lane]);
            float2 v3 = bf2_to_f2(h[(size_t)e3 * 64 + lane]);
            float2 v4 = bf2_to_f2(h[(size_t)e4 * 64 + lane]);
            float2 v5 = bf2_to_f2(h[(size_t)e5 * 64 + lane]);
            float2 v6 = bf2_to_f2(h[(size_t)e6 * 64 + lane]);
            float2 v7 = bf2_to_f2(h[(size_t)e7 * 64 + lane]);
            float2* dst2 = u ? &a1 : &a0;
            dst2->x += ((v0.x + v1.x) + (v2.x + v3.x)) + ((v4.x + v5.x) + (v6.x + v7.x));
            dst2->y += ((v0.y + v1.y) + (v2.y + v3.y)) + ((v4.y + v5.y) + (v6.y + v7.y));
        }
        acc.x += a0.x + a1.x;
        acc.y += a0.y + a1.y;
    }
    if (j + 8 <= end) {
        int e0 = eperm[j],     e1 = eperm[j + 1], e2 = eperm[j + 2], e3 = eperm[j + 3];
        int e4 = eperm[j + 4], e5 = eperm[j + 5], e6 = eperm[j + 6], e7 = eperm[j + 7];
        float2 v0 = bf2_to_f2(h[(size_t)e0 * 64 + lane]);
        float2 v1 = bf2_to_f2(h[(size_t)e1 * 64 + lane]);
        float2 v2 = bf2_to_f2(h[(size_t)e2 * 64 + lane]);
        float2 v3 = bf2_to_f2(h[(size_t)e3 * 64 + lane]);
        float2 v4 = bf2_to_f2(h[(size_t)e4 * 64 + lane]);
        float2 v5 = bf2_to_f2(h[(size_t)e5 * 64 + lane]);
        float2 v6 = bf2_to_f2(h[(size_t)e6 * 64 + lane]);
        float2 v7 = bf2_to_f2(h[(size_t)e7 * 64 + lane]);
        acc.x += ((v0.x + v1.x) + (v2.x + v3.x)) + ((v4.x + v5.x) + (v6.x + v7.x));
        acc.y += ((v0.y + v1.y) + (v2.y + v3.y)) + ((v4.y + v5.y) + (v6.y + v7.y));
        j += 8;
    }
    if (j + 4 <= end) {
        int e0 = eperm[j], e1 = eperm[j + 1], e2 = eperm[j + 2], e3 = eperm[j + 3];
        float2 v0 = bf2_to_f2(h[(size_t)e0 * 64 + lane]);
        float2 v1 = bf2_to_f2(h[(size_t)e1 * 64 + lane]);
        float2 v2 = bf2_to_f2(h[(size_t)e2 * 64 + lane]);
        float2 v3 = bf2_to_f2(h[(size_t)e3 * 64 + lane]);
        acc.x += (v0.x + v1.x) + (v2.x + v3.x);
        acc.y += (v0.y + v1.y) + (v2.y + v3.y);
        j += 4;
    }
    if (j + 2 <= end) {
        int e0 = eperm[j], e1 = eperm[j + 1];
        float2 v0 = bf2_to_f2(h[(size_t)e0 * 64 + lane]);
        float2 v1 = bf2_to_f2(h[(size_t)e1 * 64 + lane]);
        acc.x += v0.x + v1.x;
        acc.y += v0.y + v1.y;
        j += 2;
    }
    if (j < end) {
        float2 v = bf2_to_f2(h[(size_t)eperm[j] * 64 + lane]);
        acc.x += v.x;
        acc.y += v.y;
    }
    float dv = dinv[node];
    float2 bv = ((const float2*)bias)[lane];
    out[(size_t)node * 64 + lane] = pack_bf2(dv * acc.x + bv.x, dv * acc.y + bv.y);
}

// 64-wide: half-waves split the edge list (even/odd); unroll 8 per half.
__global__ __launch_bounds__(256) void k_gather64(const int* __restrict__ rp,
                                                  const int* __restrict__ deg,
                                                  const int* __restrict__ eperm,
                                                  const float* __restrict__ dinv,
                                                  const unsigned int* __restrict__ h,  // bf16x2
                                                  const float* __restrict__ bias,
                                                  float* __restrict__ out, int n) {
    int node = blockIdx.x * 4 + (threadIdx.x >> 6);
    if (node >= n) return;
    int t = threadIdx.x;
    int l32 = t & 31;
    int half = (t >> 5) & 1;
    int beg = rp[node];
    int end = beg + deg[node];
    float2 acc = make_float2(0.f, 0.f);
    if (half == 0) acc = bf2_to_f2(h[(size_t)node * 32 + l32]);  // self h'[d]
    int j = beg + half;
    for (; j + 14 < end; j += 16) {
        int e0 = eperm[j],      e1 = eperm[j + 2],  e2 = eperm[j + 4],  e3 = eperm[j + 6];
        int e4 = eperm[j + 8],  e5 = eperm[j + 10], e6 = eperm[j + 12], e7 = eperm[j + 14];
        float2 v0 = bf2_to_f2(h[(size_t)e0 * 32 + l32]);
        float2 v1 = bf2_to_f2(h[(size_t)e1 * 32 + l32]);
        float2 v2 = bf2_to_f2(h[(size_t)e2 * 32 + l32]);
        float2 v3 = bf2_to_f2(h[(size_t)e3 * 32 + l32]);
        float2 v4 = bf2_to_f2(h[(size_t)e4 * 32 + l32]);
        float2 v5 = bf2_to_f2(h[(size_t)e5 * 32 + l32]);
        float2 v6 = bf2_to_f2(h[(size_t)e6 * 32 + l32]);
        float2 v7 = bf2_to_f2(h[(size_t)e7 * 32 + l32]);
        acc.x += ((v0.x + v1.x) + (v2.x + v3.x)) + ((v4.x + v5.x) + (v6.x + v7.x));
        acc.y += ((v0.y + v1.y) + (v2.y + v3.y)) + ((v4.y + v5.y) + (v6.y + v7.y));
    }
    if (j + 6 < end) {
        int e0 = eperm[j], e1 = eperm[j + 2], e2 = eperm[j + 4], e3 = eperm[j + 6];
        float2 v0 = bf2_to_f2(h[(size_t)e0 * 32 + l32]);
        float2 v1 = bf2_to_f2(h[(size_t)e1 * 32 + l32]);
        float2 v2 = bf2_to_f2(h[(size_t)e2 * 32 + l32]);
        float2 v3 = bf2_to_f2(h[(size_t)e3 * 32 + l32]);
        acc.x += (v0.x + v1.x) + (v2.x + v3.x);
        acc.y += (v0.y + v1.y) + (v2.y + v3.y);
        j += 8;
    }
    for (; j < end; j += 2) {
        float2 v = bf2_to_f2(h[(size_t)eperm[j] * 32 + l32]);
        acc.x += v.x;
        acc.y += v.y;
    }
    acc.x += __shfl_xor(acc.x, 32);
    acc.y += __shfl_xor(acc.y, 32);
    if (half == 0) {
        float dv = dinv[node];
        float2 bv = ((const float2*)bias)[l32];
        ((float2*)out)[(size_t)node * 32 + l32] =
            make_float2(dv * acc.x + bv.x, dv * acc.y + bv.y);
    }
}

// ---------------- launch ----------------

extern "C" void kernel_launch(void* const* d_in, const int* in_sizes, int n_in,
                              void* d_out, int out_size, void* d_ws, size_t ws_size,
                              hipStream_t stream) {
    const float* x  = (const float*)d_in[0];
    const int*   ei = (const int*)d_in[1];
    const float* W1 = (const float*)d_in[2];
    const float* b1 = (const float*)d_in[3];
    const float* W2 = (const float*)d_in[4];
    const float* b2 = (const float*)d_in[5];
    float* out = (float*)d_out;

    const int N = in_sizes[0] / 128;
    const int E = in_sizes[1] / 2;
    const int* src = ei;
    const int* dst = ei + E;
    const int NB = (N + 511) >> BSHIFT;                          // coarse buckets (<= 256)
    const int cap = (E + NB - 1) / NB + ((E / NB) >> 2) + 1024;  // padded window (mean+25%+1024)

    char* ws = (char*)d_ws;
    size_t off = 0;
    auto carve = [&](size_t bytes) -> void* {
        void* p = ws + off;
        off = (off + bytes + 255) & ~(size_t)255;
        return p;
    };
    float* dinv = (float*)carve((size_t)N * 4);
    int*   rp   = (int*)carve((size_t)N * 4);
    int*   deg  = (int*)carve((size_t)N * 4);
    int*   bcur = (int*)carve(256 * 4);
    unsigned int* binned = (unsigned int*)carve((size_t)NB * cap * 4);  // packed (dlocal,src)
    int*   eperm = (int*)carve((size_t)NB * cap * 4);                   // src, bucket-windowed
    unsigned short* h    = (unsigned short*)carve((size_t)N * 128 * 2); // bf16 h' = dinv*(x@W1)
    unsigned short* hagg = (unsigned short*)carve((size_t)N * 128 * 2); // bf16 layer-1 out
    unsigned short* h2 = h;  // h dead after gather128

    const int gMm = (N + 63) / 64;
    const int ngrp = (N + 3) / 4;

    // ---- CSR build (2 kernels + 1 memset, padded windows) ----
    hipMemsetAsync(bcur, 0, 256 * sizeof(int), stream);
    k_bin<<<(E + BIN_CHUNK - 1) / BIN_CHUNK, THREADS, 0, stream>>>(src, dst, bcur, binned, E, NB, cap);
    k_node_place<<<NB, THREADS, 0, stream>>>(binned, bcur, cap, rp, deg, dinv, eperm, N);

    // ---- layer 1 ----
    k_gemm_mfma<128, false><<<gMm, THREADS, 0, stream>>>(x, W1, dinv, h, N);
    k_gather128<<<ngrp, THREADS, 0, stream>>>(rp, deg, eperm, dinv, (const unsigned int*)h, b1,
                                              (unsigned int*)hagg, N);

    // ---- layer 2 ----
    k_gemm_mfma<64, true><<<gMm, THREADS, 0, stream>>>(hagg, W2, dinv, h2, N);
    k_gather64<<<ngrp, THREADS, 0, stream>>>(rp, deg, eperm, dinv, (const unsigned int*)h2, b2, out, N);
}

// Round 2
// 294.034 us; speedup vs baseline: 1.0540x; 1.0540x over previous
//
#include <hip/hip_runtime.h>
#include <hip/hip_bf16.h>

#define THREADS 256
#define BSHIFT 9              // 512 nodes per coarse bucket; NB = ceil(N/512) <= 256
#define BIN_CHUNK 4096        // edges per k_bin block (16/thread)

typedef __attribute__((ext_vector_type(8))) short bf16x8;
typedef __attribute__((ext_vector_type(4))) float f32x4;

// ---------------- helpers ----------------

__device__ inline unsigned short f2bf(float f) {  // round-to-nearest-even
    unsigned int u = __float_as_uint(f);
    unsigned int r = (u + 0x7fffu + ((u >> 16) & 1u)) >> 16;
    return (unsigned short)r;
}

__device__ inline unsigned int pack_bf2(float x, float y) {
    return (unsigned int)f2bf(x) | ((unsigned int)f2bf(y) << 16);
}

__device__ inline float2 bf2_to_f2(unsigned int u) {  // low bf16 -> x, high bf16 -> y
    float2 r;
    r.x = __uint_as_float(u << 16);
    r.y = __uint_as_float(u & 0xffff0000u);
    return r;
}

__device__ inline unsigned short bf_relu(unsigned short v) {
    return (v & 0x8000u) ? (unsigned short)0 : v;
}

__device__ inline void accum_row(float* acc, uint4 v) {
    float2 a = bf2_to_f2(v.x), b = bf2_to_f2(v.y), c = bf2_to_f2(v.z), d = bf2_to_f2(v.w);
    acc[0] += a.x; acc[1] += a.y; acc[2] += b.x; acc[3] += b.y;
    acc[4] += c.x; acc[5] += c.y; acc[6] += d.x; acc[7] += d.y;
}

// ---------------- CSR build: padded bucket windows, packed 4B edges ----------------
// Edge record: (dst_local:9 bits << 23) | src. bcur holds zero-based counts
// (memset to 0); absolute position = b*cap + count.

__global__ __launch_bounds__(256) void k_bin(const int* __restrict__ src,
                                             const int* __restrict__ dst,
                                             int* __restrict__ bcur,
                                             unsigned int* __restrict__ binned,
                                             int E, int NB, int cap) {
    __shared__ int bcnt[256];
    __shared__ int bres[256];
    int t = threadIdx.x;
    bcnt[t] = 0;
    __syncthreads();
    int base = blockIdx.x * BIN_CHUNK;
    int sv[16], dv[16];
#pragma unroll
    for (int i = 0; i < 16; ++i) {
        int e = base + t + i * 256;
        if (e < E) {
            sv[i] = src[e];
            dv[i] = dst[e];
            atomicAdd(&bcnt[dv[i] >> BSHIFT], 1);
        } else {
            dv[i] = -1;
        }
    }
    __syncthreads();
    if (t < NB) {
        int old = bcnt[t] ? atomicAdd(&bcur[t], bcnt[t]) : 0;
        bres[t] = t * cap + old;
    }
    __syncthreads();
#pragma unroll
    for (int i = 0; i < 16; ++i) {
        if (dv[i] >= 0) {
            int b = dv[i] >> BSHIFT;
            int pos = atomicAdd(&bres[b], 1);
            if (pos < (b + 1) * cap)  // overflow guard (statistically never trips)
                binned[pos] = ((unsigned int)(dv[i] & 511) << 23) | (unsigned int)sv[i];
        }
    }
}

// per-bucket: histogram -> intra-bucket scan -> rp/deg/dinv, then place srcs
// into eperm via LDS cursors. One block per bucket; window re-read is L2-hot.
__global__ __launch_bounds__(256) void k_node_place(const unsigned int* __restrict__ binned,
                                                    const int* __restrict__ bcur, int cap,
                                                    int* __restrict__ rp,
                                                    int* __restrict__ deg,
                                                    float* __restrict__ dinv,
                                                    int* __restrict__ eperm, int N) {
    __shared__ int lc[512];
    __shared__ int s[256];
    int b = blockIdx.x;
    int t = threadIdx.x;
    int beg = b * cap;
    int end = beg + min(bcur[b], cap);
    int d0 = b << BSHIFT;
    lc[t] = 0;
    lc[t + 256] = 0;
    __syncthreads();
    for (int j = beg + t; j < end; j += 256) atomicAdd(&lc[binned[j] >> 23], 1);
    __syncthreads();
    int a = lc[2 * t], c = lc[2 * t + 1];
    int pair = a + c;
    s[t] = pair;
    __syncthreads();
    for (int off = 1; off < 256; off <<= 1) {
        int add = (t >= off) ? s[t - off] : 0;
        __syncthreads();
        s[t] += add;
        __syncthreads();
    }
    int excl = s[t] - pair;
    int st0 = beg + excl, st1 = st0 + a;
    int node0 = d0 + 2 * t;
    if (node0 < N) {
        rp[node0] = st0;
        deg[node0] = a;
        dinv[node0] = rsqrtf((float)a + 1.0f);  // +1 = self-loop
    }
    if (node0 + 1 < N) {
        rp[node0 + 1] = st1;
        deg[node0 + 1] = c;
        dinv[node0 + 1] = rsqrtf((float)c + 1.0f);
    }
    __syncthreads();
    lc[2 * t] = st0;               // repurpose lc as placement cursors
    lc[2 * t + 1] = st1;
    __syncthreads();
    for (int j = beg + t; j < end; j += 256) {
        unsigned int p = binned[j];
        int pos = atomicAdd(&lc[p >> 23], 1);
        eperm[pos] = (int)(p & 0x7fffffu);
    }
}

// ---------------- MFMA GEMM: C[M x N](bf16) = dinv[row] * (A[M x 128] @ W[128 x N]) ----
// M-tile 64 (36 KB LDS -> 4 blocks/CU; staging is latency-bound and needs the
// occupancy — the 128-tile variant at 2 blocks/CU measured slower, R13).

template <int N, bool ABF16_RELU>
__global__ __launch_bounds__(256) void k_gemm_mfma(const void* __restrict__ Av,
                                                   const float* __restrict__ W,
                                                   const float* __restrict__ dinv,
                                                   unsigned short* __restrict__ C, int M) {
    static_assert(N == 64 || N == 128, "N must be 64 or 128");
    constexpr int NT = N / 64;
    constexpr int KP = 136;
    __shared__ short As[64 * KP];
    __shared__ short Bs[N * KP];
    __shared__ float sDin[64];

    const int t = threadIdx.x;
    const int m0 = blockIdx.x * 64;

    {
        int ar = t >> 5;
        int ac = (t & 31) * 4;
#pragma unroll
        for (int rb = 0; rb < 64; rb += 8) {
            int lrow = rb + ar;
            int row = m0 + lrow;
            ushort4 sv = make_ushort4(0, 0, 0, 0);
            if (ABF16_RELU) {
                if (row < M) {
                    ushort4 u = *(const ushort4*)((const unsigned short*)Av + (size_t)row * 128 + ac);
                    sv.x = bf_relu(u.x); sv.y = bf_relu(u.y);
                    sv.z = bf_relu(u.z); sv.w = bf_relu(u.w);
                }
            } else {
                if (row < M) {
                    float4 v = *(const float4*)((const float*)Av + (size_t)row * 128 + ac);
                    sv.x = f2bf(v.x); sv.y = f2bf(v.y); sv.z = f2bf(v.z); sv.w = f2bf(v.w);
                }
            }
            *(ushort4*)&As[lrow * KP + ac] = sv;
        }
    }
    {
        constexpr int TPR = N / 4;
        constexpr int KPI = 256 / TPR;
        int bk = t / TPR;
        int bn = (t % TPR) * 4;
#pragma unroll
        for (int kb = 0; kb < 128; kb += KPI) {
            int k = kb + bk;
            float4 wv = *(const float4*)(W + (size_t)k * N + bn);
            Bs[(bn + 0) * KP + k] = f2bf(wv.x);
            Bs[(bn + 1) * KP + k] = f2bf(wv.y);
            Bs[(bn + 2) * KP + k] = f2bf(wv.z);
            Bs[(bn + 3) * KP + k] = f2bf(wv.w);
        }
    }
    if (t < 64) sDin[t] = (m0 + t < M) ? dinv[m0 + t] : 1.0f;
    __syncthreads();

    const int w = t >> 6;
    const int lane = t & 63;
    const int lm = lane & 15;
    const int qd = lane >> 4;
    const int n0w = w * 16 * NT;

    f32x4 acc[4][NT];
#pragma unroll
    for (int mi = 0; mi < 4; ++mi)
#pragma unroll
        for (int ni = 0; ni < NT; ++ni) acc[mi][ni] = (f32x4){0.f, 0.f, 0.f, 0.f};

#pragma unroll
    for (int ks = 0; ks < 4; ++ks) {
        bf16x8 a[4], b[NT];
#pragma unroll
        for (int mi = 0; mi < 4; ++mi)
            a[mi] = *(const bf16x8*)&As[(mi * 16 + lm) * KP + ks * 32 + qd * 8];
#pragma unroll
        for (int ni = 0; ni < NT; ++ni)
            b[ni] = *(const bf16x8*)&Bs[(n0w + ni * 16 + lm) * KP + ks * 32 + qd * 8];
#pragma unroll
        for (int mi = 0; mi < 4; ++mi)
#pragma unroll
            for (int ni = 0; ni < NT; ++ni)
                acc[mi][ni] = __builtin_amdgcn_mfma_f32_16x16x32_bf16(a[mi], b[ni], acc[mi][ni], 0, 0, 0);
    }

#pragma unroll
    for (int mi = 0; mi < 4; ++mi) {
#pragma unroll
        for (int ni = 0; ni < NT; ++ni) {
            int col = n0w + ni * 16 + lm;
#pragma unroll
            for (int r = 0; r < 4; ++r) {
                int lrow = mi * 16 + qd * 4 + r;
                int row = m0 + lrow;
                if (row < M) C[(size_t)row * N + col] = f2bf(sDin[lrow] * acc[mi][ni][r]);
            }
        }
    }
}

// ---------------- CSR gather, multi-chain: 4 nodes/wave, 16 lanes/node ----------------
// out[d] = dinv[d] * (sum_in h'[src] + h'[d]) + b. Edge indices fetched as one
// vector load of 16 per node (lane-parallel), broadcast via ds_bpermute; 4
// independent latency chains per wave; one row-load instr covers 4 rows.

__global__ __launch_bounds__(256) void k_gather128(const int* __restrict__ rp,
                                                   const int* __restrict__ deg,
                                                   const int* __restrict__ eperm,
                                                   const float* __restrict__ dinv,
                                                   const uint4* __restrict__ h4,  // bf16 rows: 16 uint4/row
                                                   const float* __restrict__ bias,
                                                   uint4* __restrict__ out4,      // bf16 rows
                                                   int n) {
    const int t = threadIdx.x;
    const int lane = t & 63;
    const int l16 = lane & 15;
    const int gbase = lane & 48;  // group base lane within wave
    const int node = blockIdx.x * 16 + (t >> 6) * 4 + (lane >> 4);
    const bool valid = node < n;

    int beg = 0, end = 0;
    if (valid) {
        beg = rp[node];
        end = beg + deg[node];
    }

    float acc[8];
#pragma unroll
    for (int i = 0; i < 8; ++i) acc[i] = 0.f;
    if (valid) accum_row(acc, h4[(size_t)node * 16 + l16]);  // self h'[d]

    for (int j = beg; j < end; j += 16) {
        int cnt = end - j;
        if (cnt > 16) cnt = 16;
        int ep = eperm[j + (l16 < cnt ? l16 : cnt - 1)];
        int k = 0;
        for (; k + 4 <= cnt; k += 4) {
            int i0 = __shfl(ep, gbase + k);
            int i1 = __shfl(ep, gbase + k + 1);
            int i2 = __shfl(ep, gbase + k + 2);
            int i3 = __shfl(ep, gbase + k + 3);
            uint4 v0 = h4[(size_t)i0 * 16 + l16];
            uint4 v1 = h4[(size_t)i1 * 16 + l16];
            uint4 v2 = h4[(size_t)i2 * 16 + l16];
            uint4 v3 = h4[(size_t)i3 * 16 + l16];
            accum_row(acc, v0);
            accum_row(acc, v1);
            accum_row(acc, v2);
            accum_row(acc, v3);
        }
        for (; k < cnt; ++k) {
            int i0 = __shfl(ep, gbase + k);
            uint4 v0 = h4[(size_t)i0 * 16 + l16];
            accum_row(acc, v0);
        }
    }

    if (valid) {
        float dv = dinv[node];
        float4 b0 = ((const float4*)bias)[l16 * 2];
        float4 b1 = ((const float4*)bias)[l16 * 2 + 1];
        uint4 o;
        o.x = pack_bf2(dv * acc[0] + b0.x, dv * acc[1] + b0.y);
        o.y = pack_bf2(dv * acc[2] + b0.z, dv * acc[3] + b0.w);
        o.z = pack_bf2(dv * acc[4] + b1.x, dv * acc[5] + b1.y);
        o.w = pack_bf2(dv * acc[6] + b1.z, dv * acc[7] + b1.w);
        out4[(size_t)node * 16 + l16] = o;
    }
}

// 64-feature layer: 8 nodes/wave, 8 lanes/node (rows are 128 B). fp32 output.
__global__ __launch_bounds__(256) void k_gather64(const int* __restrict__ rp,
                                                  const int* __restrict__ deg,
                                                  const int* __restrict__ eperm,
                                                  const float* __restrict__ dinv,
                                                  const uint4* __restrict__ h4,  // bf16 rows: 8 uint4/row
                                                  const float* __restrict__ bias,
                                                  float* __restrict__ out, int n) {
    const int t = threadIdx.x;
    const int lane = t & 63;
    const int l8 = lane & 7;
    const int gbase = lane & 56;
    const int node = blockIdx.x * 32 + (t >> 6) * 8 + (lane >> 3);
    const bool valid = node < n;

    int beg = 0, end = 0;
    if (valid) {
        beg = rp[node];
        end = beg + deg[node];
    }

    float acc[8];
#pragma unroll
    for (int i = 0; i < 8; ++i) acc[i] = 0.f;
    if (valid) accum_row(acc, h4[(size_t)node * 8 + l8]);  // self

    for (int j = beg; j < end; j += 8) {
        int cnt = end - j;
        if (cnt > 8) cnt = 8;
        int ep = eperm[j + (l8 < cnt ? l8 : cnt - 1)];
        int k = 0;
        for (; k + 4 <= cnt; k += 4) {
            int i0 = __shfl(ep, gbase + k);
            int i1 = __shfl(ep, gbase + k + 1);
            int i2 = __shfl(ep, gbase + k + 2);
            int i3 = __shfl(ep, gbase + k + 3);
            uint4 v0 = h4[(size_t)i0 * 8 + l8];
            uint4 v1 = h4[(size_t)i1 * 8 + l8];
            uint4 v2 = h4[(size_t)i2 * 8 + l8];
            uint4 v3 = h4[(size_t)i3 * 8 + l8];
            accum_row(acc, v0);
            accum_row(acc, v1);
            accum_row(acc, v2);
            accum_row(acc, v3);
        }
        for (; k < cnt; ++k) {
            int i0 = __shfl(ep, gbase + k);
            uint4 v0 = h4[(size_t)i0 * 8 + l8];
            accum_row(acc, v0);
        }
    }

    if (valid) {
        float dv = dinv[node];
        float4 b0 = ((const float4*)bias)[l8 * 2];
        float4 b1 = ((const float4*)bias)[l8 * 2 + 1];
        float4 o0, o1;
        o0.x = dv * acc[0] + b0.x; o0.y = dv * acc[1] + b0.y;
        o0.z = dv * acc[2] + b0.z; o0.w = dv * acc[3] + b0.w;
        o1.x = dv * acc[4] + b1.x; o1.y = dv * acc[5] + b1.y;
        o1.z = dv * acc[6] + b1.z; o1.w = dv * acc[7] + b1.w;
        float4* orow = (float4*)(out + (size_t)node * 64);
        orow[l8 * 2] = o0;
        orow[l8 * 2 + 1] = o1;
    }
}

// ---------------- launch ----------------

extern "C" void kernel_launch(void* const* d_in, const int* in_sizes, int n_in,
                              void* d_out, int out_size, void* d_ws, size_t ws_size,
                              hipStream_t stream) {
    const float* x  = (const float*)d_in[0];
    const int*   ei = (const int*)d_in[1];
    const float* W1 = (const float*)d_in[2];
    const float* b1 = (const float*)d_in[3];
    const float* W2 = (const float*)d_in[4];
    const float* b2 = (const float*)d_in[5];
    float* out = (float*)d_out;

    const int N = in_sizes[0] / 128;
    const int E = in_sizes[1] / 2;
    const int* src = ei;
    const int* dst = ei + E;
    const int NB = (N + 511) >> BSHIFT;                          // coarse buckets (<= 256)
    const int cap = (E + NB - 1) / NB + ((E / NB) >> 2) + 1024;  // padded window (mean+25%+1024)

    char* ws = (char*)d_ws;
    size_t off = 0;
    auto carve = [&](size_t bytes) -> void* {
        void* p = ws + off;
        off = (off + bytes + 255) & ~(size_t)255;
        return p;
    };
    float* dinv = (float*)carve((size_t)N * 4);
    int*   rp   = (int*)carve((size_t)N * 4);
    int*   deg  = (int*)carve((size_t)N * 4);
    int*   bcur = (int*)carve(256 * 4);
    unsigned int* binned = (unsigned int*)carve((size_t)NB * cap * 4);  // packed (dlocal,src)
    int*   eperm = (int*)carve((size_t)NB * cap * 4);                   // src, bucket-windowed
    unsigned short* h    = (unsigned short*)carve((size_t)N * 128 * 2); // bf16 h' = dinv*(x@W1)
    unsigned short* hagg = (unsigned short*)carve((size_t)N * 128 * 2); // bf16 layer-1 out
    unsigned short* h2 = h;  // h dead after gather128

    const int gMm = (N + 63) / 64;

    // ---- CSR build (2 kernels + 1 memset, padded windows) ----
    hipMemsetAsync(bcur, 0, 256 * sizeof(int), stream);
    k_bin<<<(E + BIN_CHUNK - 1) / BIN_CHUNK, THREADS, 0, stream>>>(src, dst, bcur, binned, E, NB, cap);
    k_node_place<<<NB, THREADS, 0, stream>>>(binned, bcur, cap, rp, deg, dinv, eperm, N);

    // ---- layer 1 ----
    k_gemm_mfma<128, false><<<gMm, THREADS, 0, stream>>>(x, W1, dinv, h, N);
    k_gather128<<<(N + 15) / 16, THREADS, 0, stream>>>(rp, deg, eperm, dinv, (const uint4*)h, b1,
                                                       (uint4*)hagg, N);

    // ---- layer 2 ----
    k_gemm_mfma<64, true><<<gMm, THREADS, 0, stream>>>(hagg, W2, dinv, h2, N);
    k_gather64<<<(N + 31) / 32, THREADS, 0, stream>>>(rp, deg, eperm, dinv, (const uint4*)h2, b2, out, N);
}

// Round 3
// 290.909 us; speedup vs baseline: 1.0653x; 1.0107x over previous
//
#include <hip/hip_runtime.h>
#include <hip/hip_bf16.h>

#define THREADS 256
#define BSHIFT 9              // 512 nodes per coarse bucket; NB = ceil(N/512) <= 256
#define BIN_CHUNK 4096        // edges per k_bin block (16/thread)

typedef __attribute__((ext_vector_type(8))) short bf16x8;
typedef __attribute__((ext_vector_type(4))) float f32x4;

// ---------------- helpers ----------------

__device__ inline unsigned short f2bf(float f) {  // round-to-nearest-even
    unsigned int u = __float_as_uint(f);
    unsigned int r = (u + 0x7fffu + ((u >> 16) & 1u)) >> 16;
    return (unsigned short)r;
}

__device__ inline unsigned int pack_bf2(float x, float y) {
    return (unsigned int)f2bf(x) | ((unsigned int)f2bf(y) << 16);
}

__device__ inline float2 bf2_to_f2(unsigned int u) {  // low bf16 -> x, high bf16 -> y
    float2 r;
    r.x = __uint_as_float(u << 16);
    r.y = __uint_as_float(u & 0xffff0000u);
    return r;
}

__device__ inline unsigned short bf_relu(unsigned short v) {
    return (v & 0x8000u) ? (unsigned short)0 : v;
}

__device__ inline void accum_row(float* acc, uint4 v) {
    float2 a = bf2_to_f2(v.x), b = bf2_to_f2(v.y), c = bf2_to_f2(v.z), d = bf2_to_f2(v.w);
    acc[0] += a.x; acc[1] += a.y; acc[2] += b.x; acc[3] += b.y;
    acc[4] += c.x; acc[5] += c.y; acc[6] += d.x; acc[7] += d.y;
}

// ---------------- CSR build: padded bucket windows, packed 4B edges ----------------
// Edge record: (dst_local:9 bits << 23) | src. bcur holds zero-based counts
// (memset to 0); absolute position = b*cap + count.

__global__ __launch_bounds__(256) void k_bin(const int* __restrict__ src,
                                             const int* __restrict__ dst,
                                             int* __restrict__ bcur,
                                             unsigned int* __restrict__ binned,
                                             int E, int NB, int cap) {
    __shared__ int bcnt[256];
    __shared__ int bres[256];
    int t = threadIdx.x;
    bcnt[t] = 0;
    __syncthreads();
    int base = blockIdx.x * BIN_CHUNK;
    int sv[16], dv[16];
#pragma unroll
    for (int i = 0; i < 16; ++i) {
        int e = base + t + i * 256;
        if (e < E) {
            sv[i] = src[e];
            dv[i] = dst[e];
            atomicAdd(&bcnt[dv[i] >> BSHIFT], 1);
        } else {
            dv[i] = -1;
        }
    }
    __syncthreads();
    if (t < NB) {
        int old = bcnt[t] ? atomicAdd(&bcur[t], bcnt[t]) : 0;
        bres[t] = t * cap + old;
    }
    __syncthreads();
#pragma unroll
    for (int i = 0; i < 16; ++i) {
        if (dv[i] >= 0) {
            int b = dv[i] >> BSHIFT;
            int pos = atomicAdd(&bres[b], 1);
            if (pos < (b + 1) * cap)  // overflow guard (statistically never trips)
                binned[pos] = ((unsigned int)(dv[i] & 511) << 23) | (unsigned int)sv[i];
        }
    }
}

// per-bucket: histogram -> intra-bucket scan -> rp/deg/dinv, then place srcs
// into eperm via LDS cursors. One block per bucket; window re-read is L2-hot.
__global__ __launch_bounds__(256) void k_node_place(const unsigned int* __restrict__ binned,
                                                    const int* __restrict__ bcur, int cap,
                                                    int* __restrict__ rp,
                                                    int* __restrict__ deg,
                                                    float* __restrict__ dinv,
                                                    int* __restrict__ eperm, int N) {
    __shared__ int lc[512];
    __shared__ int s[256];
    int b = blockIdx.x;
    int t = threadIdx.x;
    int beg = b * cap;
    int end = beg + min(bcur[b], cap);
    int d0 = b << BSHIFT;
    lc[t] = 0;
    lc[t + 256] = 0;
    __syncthreads();
    for (int j = beg + t; j < end; j += 256) atomicAdd(&lc[binned[j] >> 23], 1);
    __syncthreads();
    int a = lc[2 * t], c = lc[2 * t + 1];
    int pair = a + c;
    s[t] = pair;
    __syncthreads();
    for (int off = 1; off < 256; off <<= 1) {
        int add = (t >= off) ? s[t - off] : 0;
        __syncthreads();
        s[t] += add;
        __syncthreads();
    }
    int excl = s[t] - pair;
    int st0 = beg + excl, st1 = st0 + a;
    int node0 = d0 + 2 * t;
    if (node0 < N) {
        rp[node0] = st0;
        deg[node0] = a;
        dinv[node0] = rsqrtf((float)a + 1.0f);  // +1 = self-loop
    }
    if (node0 + 1 < N) {
        rp[node0 + 1] = st1;
        deg[node0 + 1] = c;
        dinv[node0 + 1] = rsqrtf((float)c + 1.0f);
    }
    __syncthreads();
    lc[2 * t] = st0;               // repurpose lc as placement cursors
    lc[2 * t + 1] = st1;
    __syncthreads();
    for (int j = beg + t; j < end; j += 256) {
        unsigned int p = binned[j];
        int pos = atomicAdd(&lc[p >> 23], 1);
        eperm[pos] = (int)(p & 0x7fffffu);
    }
}

// ---------------- MFMA GEMM: C[M x N](bf16) = dinv[row] * (A[M x 128] @ W[128 x N]) ----
// M-tile 64 (36 KB LDS -> 4 blocks/CU; staging is latency-bound and needs the
// occupancy — the 128-tile variant at 2 blocks/CU measured slower, R13).

template <int N, bool ABF16_RELU>
__global__ __launch_bounds__(256) void k_gemm_mfma(const void* __restrict__ Av,
                                                   const float* __restrict__ W,
                                                   const float* __restrict__ dinv,
                                                   unsigned short* __restrict__ C, int M) {
    static_assert(N == 64 || N == 128, "N must be 64 or 128");
    constexpr int NT = N / 64;
    constexpr int KP = 136;
    __shared__ short As[64 * KP];
    __shared__ short Bs[N * KP];
    __shared__ float sDin[64];

    const int t = threadIdx.x;
    const int m0 = blockIdx.x * 64;

    {
        int ar = t >> 5;
        int ac = (t & 31) * 4;
#pragma unroll
        for (int rb = 0; rb < 64; rb += 8) {
            int lrow = rb + ar;
            int row = m0 + lrow;
            ushort4 sv = make_ushort4(0, 0, 0, 0);
            if (ABF16_RELU) {
                if (row < M) {
                    ushort4 u = *(const ushort4*)((const unsigned short*)Av + (size_t)row * 128 + ac);
                    sv.x = bf_relu(u.x); sv.y = bf_relu(u.y);
                    sv.z = bf_relu(u.z); sv.w = bf_relu(u.w);
                }
            } else {
                if (row < M) {
                    float4 v = *(const float4*)((const float*)Av + (size_t)row * 128 + ac);
                    sv.x = f2bf(v.x); sv.y = f2bf(v.y); sv.z = f2bf(v.z); sv.w = f2bf(v.w);
                }
            }
            *(ushort4*)&As[lrow * KP + ac] = sv;
        }
    }
    {
        constexpr int TPR = N / 4;
        constexpr int KPI = 256 / TPR;
        int bk = t / TPR;
        int bn = (t % TPR) * 4;
#pragma unroll
        for (int kb = 0; kb < 128; kb += KPI) {
            int k = kb + bk;
            float4 wv = *(const float4*)(W + (size_t)k * N + bn);
            Bs[(bn + 0) * KP + k] = f2bf(wv.x);
            Bs[(bn + 1) * KP + k] = f2bf(wv.y);
            Bs[(bn + 2) * KP + k] = f2bf(wv.z);
            Bs[(bn + 3) * KP + k] = f2bf(wv.w);
        }
    }
    if (t < 64) sDin[t] = (m0 + t < M) ? dinv[m0 + t] : 1.0f;
    __syncthreads();

    const int w = t >> 6;
    const int lane = t & 63;
    const int lm = lane & 15;
    const int qd = lane >> 4;
    const int n0w = w * 16 * NT;

    f32x4 acc[4][NT];
#pragma unroll
    for (int mi = 0; mi < 4; ++mi)
#pragma unroll
        for (int ni = 0; ni < NT; ++ni) acc[mi][ni] = (f32x4){0.f, 0.f, 0.f, 0.f};

#pragma unroll
    for (int ks = 0; ks < 4; ++ks) {
        bf16x8 a[4], b[NT];
#pragma unroll
        for (int mi = 0; mi < 4; ++mi)
            a[mi] = *(const bf16x8*)&As[(mi * 16 + lm) * KP + ks * 32 + qd * 8];
#pragma unroll
        for (int ni = 0; ni < NT; ++ni)
            b[ni] = *(const bf16x8*)&Bs[(n0w + ni * 16 + lm) * KP + ks * 32 + qd * 8];
#pragma unroll
        for (int mi = 0; mi < 4; ++mi)
#pragma unroll
            for (int ni = 0; ni < NT; ++ni)
                acc[mi][ni] = __builtin_amdgcn_mfma_f32_16x16x32_bf16(a[mi], b[ni], acc[mi][ni], 0, 0, 0);
    }

#pragma unroll
    for (int mi = 0; mi < 4; ++mi) {
#pragma unroll
        for (int ni = 0; ni < NT; ++ni) {
            int col = n0w + ni * 16 + lm;
#pragma unroll
            for (int r = 0; r < 4; ++r) {
                int lrow = mi * 16 + qd * 4 + r;
                int row = m0 + lrow;
                if (row < M) C[(size_t)row * N + col] = f2bf(sDin[lrow] * acc[mi][ni][r]);
            }
        }
    }
}

// ---------------- CSR gather, multi-chain + deep MLP: 4 nodes/wave, 16 lanes/node ------
// Full 16-edge batches issue ALL 16 row loads back-to-back (16 KB in flight per
// wave) before accumulating; compiler's progressive vmcnt overlaps returns with
// the FMA chain. Arrays are statically indexed only (no scratch).

__global__ __launch_bounds__(256) void k_gather128(const int* __restrict__ rp,
                                                   const int* __restrict__ deg,
                                                   const int* __restrict__ eperm,
                                                   const float* __restrict__ dinv,
                                                   const uint4* __restrict__ h4,  // bf16 rows: 16 uint4/row
                                                   const float* __restrict__ bias,
                                                   uint4* __restrict__ out4,      // bf16 rows
                                                   int n) {
    const int t = threadIdx.x;
    const int lane = t & 63;
    const int l16 = lane & 15;
    const int gbase = lane & 48;  // group base lane within wave
    const int node = blockIdx.x * 16 + (t >> 6) * 4 + (lane >> 4);
    const bool valid = node < n;

    int beg = 0, end = 0;
    if (valid) {
        beg = rp[node];
        end = beg + deg[node];
    }

    float acc[8];
#pragma unroll
    for (int i = 0; i < 8; ++i) acc[i] = 0.f;
    if (valid) accum_row(acc, h4[(size_t)node * 16 + l16]);  // self h'[d]

    int j = beg;
    // ---- full 16-edge batches: 1 index load + 16 row loads in flight ----
    for (; j + 16 <= end; j += 16) {
        int ep = eperm[j + l16];
        int idx[16];
#pragma unroll
        for (int k = 0; k < 16; ++k) idx[k] = __shfl(ep, gbase + k);
        uint4 v[16];
#pragma unroll
        for (int k = 0; k < 16; ++k) v[k] = h4[(size_t)idx[k] * 16 + l16];
#pragma unroll
        for (int k = 0; k < 16; ++k) accum_row(acc, v[k]);
    }
    // ---- remainder (< 16 edges) ----
    int cnt = end - j;
    if (cnt > 0) {
        int ep = eperm[j + (l16 < cnt ? l16 : cnt - 1)];
        int k = 0;
        for (; k + 4 <= cnt; k += 4) {
            int i0 = __shfl(ep, gbase + k);
            int i1 = __shfl(ep, gbase + k + 1);
            int i2 = __shfl(ep, gbase + k + 2);
            int i3 = __shfl(ep, gbase + k + 3);
            uint4 v0 = h4[(size_t)i0 * 16 + l16];
            uint4 v1 = h4[(size_t)i1 * 16 + l16];
            uint4 v2 = h4[(size_t)i2 * 16 + l16];
            uint4 v3 = h4[(size_t)i3 * 16 + l16];
            accum_row(acc, v0);
            accum_row(acc, v1);
            accum_row(acc, v2);
            accum_row(acc, v3);
        }
        for (; k < cnt; ++k) {
            int i0 = __shfl(ep, gbase + k);
            uint4 v0 = h4[(size_t)i0 * 16 + l16];
            accum_row(acc, v0);
        }
    }

    if (valid) {
        float dv = dinv[node];
        float4 b0 = ((const float4*)bias)[l16 * 2];
        float4 b1 = ((const float4*)bias)[l16 * 2 + 1];
        uint4 o;
        o.x = pack_bf2(dv * acc[0] + b0.x, dv * acc[1] + b0.y);
        o.y = pack_bf2(dv * acc[2] + b0.z, dv * acc[3] + b0.w);
        o.z = pack_bf2(dv * acc[4] + b1.x, dv * acc[5] + b1.y);
        o.w = pack_bf2(dv * acc[6] + b1.z, dv * acc[7] + b1.w);
        out4[(size_t)node * 16 + l16] = o;
    }
}

// 64-feature layer: 8 nodes/wave, 8 lanes/node (rows are 128 B). fp32 output.
// 16-edge batches: 2 index loads + 16 row loads in flight.
__global__ __launch_bounds__(256) void k_gather64(const int* __restrict__ rp,
                                                  const int* __restrict__ deg,
                                                  const int* __restrict__ eperm,
                                                  const float* __restrict__ dinv,
                                                  const uint4* __restrict__ h4,  // bf16 rows: 8 uint4/row
                                                  const float* __restrict__ bias,
                                                  float* __restrict__ out, int n) {
    const int t = threadIdx.x;
    const int lane = t & 63;
    const int l8 = lane & 7;
    const int gbase = lane & 56;
    const int node = blockIdx.x * 32 + (t >> 6) * 8 + (lane >> 3);
    const bool valid = node < n;

    int beg = 0, end = 0;
    if (valid) {
        beg = rp[node];
        end = beg + deg[node];
    }

    float acc[8];
#pragma unroll
    for (int i = 0; i < 8; ++i) acc[i] = 0.f;
    if (valid) accum_row(acc, h4[(size_t)node * 8 + l8]);  // self

    int j = beg;
    // ---- full 16-edge batches ----
    for (; j + 16 <= end; j += 16) {
        int ep0 = eperm[j + l8];
        int ep1 = eperm[j + 8 + l8];
        int idx[16];
#pragma unroll
        for (int k = 0; k < 8; ++k) idx[k] = __shfl(ep0, gbase + k);
#pragma unroll
        for (int k = 0; k < 8; ++k) idx[8 + k] = __shfl(ep1, gbase + k);
        uint4 v[16];
#pragma unroll
        for (int k = 0; k < 16; ++k) v[k] = h4[(size_t)idx[k] * 8 + l8];
#pragma unroll
        for (int k = 0; k < 16; ++k) accum_row(acc, v[k]);
    }
    int cnt = end - j;
    // ---- one 8-edge batch if present ----
    if (cnt >= 8) {
        int ep = eperm[j + l8];
        int idx[8];
#pragma unroll
        for (int k = 0; k < 8; ++k) idx[k] = __shfl(ep, gbase + k);
        uint4 v[8];
#pragma unroll
        for (int k = 0; k < 8; ++k) v[k] = h4[(size_t)idx[k] * 8 + l8];
#pragma unroll
        for (int k = 0; k < 8; ++k) accum_row(acc, v[k]);
        j += 8;
        cnt -= 8;
    }
    // ---- remainder (< 8 edges) ----
    if (cnt > 0) {
        int ep = eperm[j + (l8 < cnt ? l8 : cnt - 1)];
        int k = 0;
        for (; k + 4 <= cnt; k += 4) {
            int i0 = __shfl(ep, gbase + k);
            int i1 = __shfl(ep, gbase + k + 1);
            int i2 = __shfl(ep, gbase + k + 2);
            int i3 = __shfl(ep, gbase + k + 3);
            uint4 v0 = h4[(size_t)i0 * 8 + l8];
            uint4 v1 = h4[(size_t)i1 * 8 + l8];
            uint4 v2 = h4[(size_t)i2 * 8 + l8];
            uint4 v3 = h4[(size_t)i3 * 8 + l8];
            accum_row(acc, v0);
            accum_row(acc, v1);
            accum_row(acc, v2);
            accum_row(acc, v3);
        }
        for (; k < cnt; ++k) {
            int i0 = __shfl(ep, gbase + k);
            uint4 v0 = h4[(size_t)i0 * 8 + l8];
            accum_row(acc, v0);
        }
    }

    if (valid) {
        float dv = dinv[node];
        float4 b0 = ((const float4*)bias)[l8 * 2];
        float4 b1 = ((const float4*)bias)[l8 * 2 + 1];
        float4 o0, o1;
        o0.x = dv * acc[0] + b0.x; o0.y = dv * acc[1] + b0.y;
        o0.z = dv * acc[2] + b0.z; o0.w = dv * acc[3] + b0.w;
        o1.x = dv * acc[4] + b1.x; o1.y = dv * acc[5] + b1.y;
        o1.z = dv * acc[6] + b1.z; o1.w = dv * acc[7] + b1.w;
        float4* orow = (float4*)(out + (size_t)node * 64);
        orow[l8 * 2] = o0;
        orow[l8 * 2 + 1] = o1;
    }
}

// ---------------- launch ----------------

extern "C" void kernel_launch(void* const* d_in, const int* in_sizes, int n_in,
                              void* d_out, int out_size, void* d_ws, size_t ws_size,
                              hipStream_t stream) {
    const float* x  = (const float*)d_in[0];
    const int*   ei = (const int*)d_in[1];
    const float* W1 = (const float*)d_in[2];
    const float* b1 = (const float*)d_in[3];
    const float* W2 = (const float*)d_in[4];
    const float* b2 = (const float*)d_in[5];
    float* out = (float*)d_out;

    const int N = in_sizes[0] / 128;
    const int E = in_sizes[1] / 2;
    const int* src = ei;
    const int* dst = ei + E;
    const int NB = (N + 511) >> BSHIFT;                          // coarse buckets (<= 256)
    const int cap = (E + NB - 1) / NB + ((E / NB) >> 2) + 1024;  // padded window (mean+25%+1024)

    char* ws = (char*)d_ws;
    size_t off = 0;
    auto carve = [&](size_t bytes) -> void* {
        void* p = ws + off;
        off = (off + bytes + 255) & ~(size_t)255;
        return p;
    };
    float* dinv = (float*)carve((size_t)N * 4);
    int*   rp   = (int*)carve((size_t)N * 4);
    int*   deg  = (int*)carve((size_t)N * 4);
    int*   bcur = (int*)carve(256 * 4);
    unsigned int* binned = (unsigned int*)carve((size_t)NB * cap * 4);  // packed (dlocal,src)
    int*   eperm = (int*)carve((size_t)NB * cap * 4);                   // src, bucket-windowed
    unsigned short* h    = (unsigned short*)carve((size_t)N * 128 * 2); // bf16 h' = dinv*(x@W1)
    unsigned short* hagg = (unsigned short*)carve((size_t)N * 128 * 2); // bf16 layer-1 out
    unsigned short* h2 = h;  // h dead after gather128

    const int gMm = (N + 63) / 64;

    // ---- CSR build (2 kernels + 1 memset, padded windows) ----
    hipMemsetAsync(bcur, 0, 256 * sizeof(int), stream);
    k_bin<<<(E + BIN_CHUNK - 1) / BIN_CHUNK, THREADS, 0, stream>>>(src, dst, bcur, binned, E, NB, cap);
    k_node_place<<<NB, THREADS, 0, stream>>>(binned, bcur, cap, rp, deg, dinv, eperm, N);

    // ---- layer 1 ----
    k_gemm_mfma<128, false><<<gMm, THREADS, 0, stream>>>(x, W1, dinv, h, N);
    k_gather128<<<(N + 15) / 16, THREADS, 0, stream>>>(rp, deg, eperm, dinv, (const uint4*)h, b1,
                                                       (uint4*)hagg, N);

    // ---- layer 2 ----
    k_gemm_mfma<64, true><<<gMm, THREADS, 0, stream>>>(hagg, W2, dinv, h2, N);
    k_gather64<<<(N + 31) / 32, THREADS, 0, stream>>>(rp, deg, eperm, dinv, (const uint4*)h2, b2, out, N);
}

// Round 4
// 274.999 us; speedup vs baseline: 1.1269x; 1.0579x over previous
//
#include <hip/hip_runtime.h>
#include <hip/hip_bf16.h>

#define THREADS 256
#define BSHIFT 9              // 512 nodes per coarse bucket; NB = ceil(N/512) <= 256
#define BIN_CHUNK 4096        // edges per k_bin block (16/thread)
#define KP 136                // padded LDS row stride (shorts)

typedef __attribute__((ext_vector_type(8))) short bf16x8;
typedef __attribute__((ext_vector_type(4))) float f32x4;

// ---------------- helpers ----------------

__device__ inline unsigned short f2bf(float f) {  // round-to-nearest-even
    unsigned int u = __float_as_uint(f);
    unsigned int r = (u + 0x7fffu + ((u >> 16) & 1u)) >> 16;
    return (unsigned short)r;
}

__device__ inline float2 bf2_to_f2(unsigned int u) {  // low bf16 -> x, high bf16 -> y
    float2 r;
    r.x = __uint_as_float(u << 16);
    r.y = __uint_as_float(u & 0xffff0000u);
    return r;
}

__device__ inline void accum_row(float* acc, uint4 v) {
    float2 a = bf2_to_f2(v.x), b = bf2_to_f2(v.y), c = bf2_to_f2(v.z), d = bf2_to_f2(v.w);
    acc[0] += a.x; acc[1] += a.y; acc[2] += b.x; acc[3] += b.y;
    acc[4] += c.x; acc[5] += c.y; acc[6] += d.x; acc[7] += d.y;
}

__device__ inline void accum_row_scaled(float* acc, uint4 v, float s) {
    float2 a = bf2_to_f2(v.x), b = bf2_to_f2(v.y), c = bf2_to_f2(v.z), d = bf2_to_f2(v.w);
    acc[0] = fmaf(s, a.x, acc[0]); acc[1] = fmaf(s, a.y, acc[1]);
    acc[2] = fmaf(s, b.x, acc[2]); acc[3] = fmaf(s, b.y, acc[3]);
    acc[4] = fmaf(s, c.x, acc[4]); acc[5] = fmaf(s, c.y, acc[5]);
    acc[6] = fmaf(s, d.x, acc[6]); acc[7] = fmaf(s, d.y, acc[7]);
}

// ---------------- fused: edge binning (blocks [0,nbin)) + layer-1 GEMM (rest) ---------
// Bin role: edge record (dst_local:9 << 23) | src into padded bucket windows.
// GEMM role: h[M x 128](bf16) = x[M x 128] @ W1  (NO dinv scale — deferred to
// gather so this is independent of the CSR build and can overlap it).

__global__ __launch_bounds__(256) void k_bin_gemm1(const int* __restrict__ src,
                                                   const int* __restrict__ dst,
                                                   int* __restrict__ bcur,
                                                   unsigned int* __restrict__ binned,
                                                   int E, int NB, int cap,
                                                   const float* __restrict__ x,
                                                   const float* __restrict__ W1,
                                                   unsigned short* __restrict__ h,
                                                   int M, int nbin) {
    __shared__ __align__(16) char smem[64 * KP * 2 + 128 * KP * 2];  // 52,224 B
    const int t = threadIdx.x;

    if ((int)blockIdx.x < nbin) {
        // ---------------- bin role ----------------
        int* bcnt = (int*)smem;
        int* bres = bcnt + 256;
        bcnt[t] = 0;
        __syncthreads();
        int base = blockIdx.x * BIN_CHUNK;
        int sv[16], dv[16];
#pragma unroll
        for (int i = 0; i < 16; ++i) {
            int e = base + t + i * 256;
            if (e < E) {
                sv[i] = src[e];
                dv[i] = dst[e];
                atomicAdd(&bcnt[dv[i] >> BSHIFT], 1);
            } else {
                dv[i] = -1;
            }
        }
        __syncthreads();
        if (t < NB) {
            int old = bcnt[t] ? atomicAdd(&bcur[t], bcnt[t]) : 0;
            bres[t] = t * cap + old;
        }
        __syncthreads();
#pragma unroll
        for (int i = 0; i < 16; ++i) {
            if (dv[i] >= 0) {
                int b = dv[i] >> BSHIFT;
                int pos = atomicAdd(&bres[b], 1);
                if (pos < (b + 1) * cap)  // overflow guard (statistically never trips)
                    binned[pos] = ((unsigned int)(dv[i] & 511) << 23) | (unsigned int)sv[i];
            }
        }
        return;
    }

    // ---------------- GEMM role: 64-row tile of h = x @ W1 ----------------
    short* As = (short*)smem;              // [64][KP]
    short* Bs = (short*)(smem + 64 * KP * 2);  // [128][KP]
    const int m0 = ((int)blockIdx.x - nbin) * 64;

    {
        int ar = t >> 5;
        int ac = (t & 31) * 4;
#pragma unroll
        for (int rb = 0; rb < 64; rb += 8) {
            int lrow = rb + ar;
            int row = m0 + lrow;
            ushort4 sv = make_ushort4(0, 0, 0, 0);
            if (row < M) {
                float4 v = *(const float4*)(x + (size_t)row * 128 + ac);
                sv.x = f2bf(v.x); sv.y = f2bf(v.y); sv.z = f2bf(v.z); sv.w = f2bf(v.w);
            }
            *(ushort4*)&As[lrow * KP + ac] = sv;
        }
    }
    {
        int bk = t / 32;          // 0..7
        int bn = (t % 32) * 4;    // 0..124
#pragma unroll
        for (int kb = 0; kb < 128; kb += 8) {
            int k = kb + bk;
            float4 wv = *(const float4*)(W1 + (size_t)k * 128 + bn);
            Bs[(bn + 0) * KP + k] = f2bf(wv.x);
            Bs[(bn + 1) * KP + k] = f2bf(wv.y);
            Bs[(bn + 2) * KP + k] = f2bf(wv.z);
            Bs[(bn + 3) * KP + k] = f2bf(wv.w);
        }
    }
    __syncthreads();

    const int w = t >> 6;
    const int lane = t & 63;
    const int lm = lane & 15;
    const int qd = lane >> 4;
    const int n0w = w * 32;

    f32x4 acc[4][2];
#pragma unroll
    for (int mi = 0; mi < 4; ++mi)
#pragma unroll
        for (int ni = 0; ni < 2; ++ni) acc[mi][ni] = (f32x4){0.f, 0.f, 0.f, 0.f};

#pragma unroll
    for (int ks = 0; ks < 4; ++ks) {
        bf16x8 a[4], b[2];
#pragma unroll
        for (int mi = 0; mi < 4; ++mi)
            a[mi] = *(const bf16x8*)&As[(mi * 16 + lm) * KP + ks * 32 + qd * 8];
#pragma unroll
        for (int ni = 0; ni < 2; ++ni)
            b[ni] = *(const bf16x8*)&Bs[(n0w + ni * 16 + lm) * KP + ks * 32 + qd * 8];
#pragma unroll
        for (int mi = 0; mi < 4; ++mi)
#pragma unroll
            for (int ni = 0; ni < 2; ++ni)
                acc[mi][ni] = __builtin_amdgcn_mfma_f32_16x16x32_bf16(a[mi], b[ni], acc[mi][ni], 0, 0, 0);
    }

#pragma unroll
    for (int mi = 0; mi < 4; ++mi) {
#pragma unroll
        for (int ni = 0; ni < 2; ++ni) {
            int col = n0w + ni * 16 + lm;
#pragma unroll
            for (int r = 0; r < 4; ++r) {
                int lrow = mi * 16 + qd * 4 + r;
                int row = m0 + lrow;
                if (row < M) h[(size_t)row * 128 + col] = f2bf(acc[mi][ni][r]);
            }
        }
    }
}

// per-bucket: histogram -> intra-bucket scan -> rp/deg/dinv, then place srcs
// into eperm via LDS cursors. One block per bucket; window re-read is L2-hot.
__global__ __launch_bounds__(256) void k_node_place(const unsigned int* __restrict__ binned,
                                                    const int* __restrict__ bcur, int cap,
                                                    int* __restrict__ rp,
                                                    int* __restrict__ deg,
                                                    float* __restrict__ dinv,
                                                    int* __restrict__ eperm, int N) {
    __shared__ int lc[512];
    __shared__ int s[256];
    int b = blockIdx.x;
    int t = threadIdx.x;
    int beg = b * cap;
    int end = beg + min(bcur[b], cap);
    int d0 = b << BSHIFT;
    lc[t] = 0;
    lc[t + 256] = 0;
    __syncthreads();
    for (int j = beg + t; j < end; j += 256) atomicAdd(&lc[binned[j] >> 23], 1);
    __syncthreads();
    int a = lc[2 * t], c = lc[2 * t + 1];
    int pair = a + c;
    s[t] = pair;
    __syncthreads();
    for (int off = 1; off < 256; off <<= 1) {
        int add = (t >= off) ? s[t - off] : 0;
        __syncthreads();
        s[t] += add;
        __syncthreads();
    }
    int excl = s[t] - pair;
    int st0 = beg + excl, st1 = st0 + a;
    int node0 = d0 + 2 * t;
    if (node0 < N) {
        rp[node0] = st0;
        deg[node0] = a;
        dinv[node0] = rsqrtf((float)a + 1.0f);  // +1 = self-loop
    }
    if (node0 + 1 < N) {
        rp[node0 + 1] = st1;
        deg[node0 + 1] = c;
        dinv[node0 + 1] = rsqrtf((float)c + 1.0f);
    }
    __syncthreads();
    lc[2 * t] = st0;               // repurpose lc as placement cursors
    lc[2 * t + 1] = st1;
    __syncthreads();
    for (int j = beg + t; j < end; j += 256) {
        unsigned int p = binned[j];
        int pos = atomicAdd(&lc[p >> 23], 1);
        eperm[pos] = (int)(p & 0x7fffffu);
    }
}

// ---------------- fused: layer-1 gather + layer-2 GEMM ----------------
// Block owns 64 nodes. Gather phase (4 rounds x 4 waves x 4 nodes): for node d,
// agg = sum_e dinv[src_e]*h[src_e] + dinv[d]*h[d]; row = relu(dinv[d]*agg + b1)
// -> bf16 -> LDS tile As[64][128]. GEMM phase: h2 = dinv[row]*(As @ W2) (bf16).
// Gather is fetch-throughput-capped (~3.5 TB/s L2-miss path, R2/R3 evidence);
// the MFMA tail hides under it and the 51 MB hagg round-trip disappears.

__global__ __launch_bounds__(256) void k_gather_gemm2(const int* __restrict__ rp,
                                                      const int* __restrict__ deg,
                                                      const int* __restrict__ eperm,
                                                      const float* __restrict__ dinv,
                                                      const uint4* __restrict__ h4,  // bf16 rows: 16 uint4
                                                      const float* __restrict__ b1,
                                                      const float* __restrict__ W2,
                                                      unsigned short* __restrict__ h2,  // bf16 [n x 64]
                                                      int n) {
    __shared__ short As[64 * KP];
    __shared__ short Bs[64 * KP];
    __shared__ float sDin[64];

    const int t = threadIdx.x;
    const int lane = t & 63;
    const int l16 = lane & 15;
    const int gbase = lane & 48;
    const int m0 = blockIdx.x * 64;

    // stage W2 (128x64 fp32 -> bf16), col-major-by-row layout like gemm64's Bs
    {
        int bk = t / 16;          // 0..15
        int bn = (t % 16) * 4;    // 0..60
#pragma unroll
        for (int kb = 0; kb < 128; kb += 16) {
            int k = kb + bk;
            float4 wv = *(const float4*)(W2 + (size_t)k * 64 + bn);
            Bs[(bn + 0) * KP + k] = f2bf(wv.x);
            Bs[(bn + 1) * KP + k] = f2bf(wv.y);
            Bs[(bn + 2) * KP + k] = f2bf(wv.z);
            Bs[(bn + 3) * KP + k] = f2bf(wv.w);
        }
    }
    if (t < 64) sDin[t] = (m0 + t < n) ? dinv[m0 + t] : 1.0f;

    // gather rounds: 4 waves x 4 lane-groups x 4 rounds = 64 nodes
#pragma unroll 1
    for (int r = 0; r < 4; ++r) {
        const int lrow = r * 16 + ((t >> 6) << 2) + (lane >> 4);
        const int node = m0 + lrow;
        const bool valid = node < n;

        int beg = 0, end = 0;
        float dv_self = 0.f;
        if (valid) {
            beg = rp[node];
            end = beg + deg[node];
            dv_self = dinv[node];
        }

        float acc[8];
#pragma unroll
        for (int i = 0; i < 8; ++i) acc[i] = 0.f;
        if (valid) accum_row_scaled(acc, h4[(size_t)node * 16 + l16], dv_self);  // self-loop

        for (int j = beg; j < end; j += 16) {
            int cnt = end - j;
            if (cnt > 16) cnt = 16;
            int ep = eperm[j + (l16 < cnt ? l16 : cnt - 1)];
            float dvv = dinv[ep];
            int k = 0;
            for (; k + 4 <= cnt; k += 4) {
                int i0 = __shfl(ep, gbase + k);
                int i1 = __shfl(ep, gbase + k + 1);
                int i2 = __shfl(ep, gbase + k + 2);
                int i3 = __shfl(ep, gbase + k + 3);
                float d0 = __shfl(dvv, gbase + k);
                float d1 = __shfl(dvv, gbase + k + 1);
                float d2 = __shfl(dvv, gbase + k + 2);
                float d3 = __shfl(dvv, gbase + k + 3);
                uint4 v0 = h4[(size_t)i0 * 16 + l16];
                uint4 v1 = h4[(size_t)i1 * 16 + l16];
                uint4 v2 = h4[(size_t)i2 * 16 + l16];
                uint4 v3 = h4[(size_t)i3 * 16 + l16];
                accum_row_scaled(acc, v0, d0);
                accum_row_scaled(acc, v1, d1);
                accum_row_scaled(acc, v2, d2);
                accum_row_scaled(acc, v3, d3);
            }
            for (; k < cnt; ++k) {
                int i0 = __shfl(ep, gbase + k);
                float d0 = __shfl(dvv, gbase + k);
                uint4 v0 = h4[(size_t)i0 * 16 + l16];
                accum_row_scaled(acc, v0, d0);
            }
        }

        // layer-1 epilogue: relu(dinv*agg + b1) -> bf16 -> LDS
        float4 bb0 = ((const float4*)b1)[l16 * 2];
        float4 bb1 = ((const float4*)b1)[l16 * 2 + 1];
        float o0 = fmaxf(fmaf(dv_self, acc[0], bb0.x), 0.f);
        float o1 = fmaxf(fmaf(dv_self, acc[1], bb0.y), 0.f);
        float o2 = fmaxf(fmaf(dv_self, acc[2], bb0.z), 0.f);
        float o3 = fmaxf(fmaf(dv_self, acc[3], bb0.w), 0.f);
        float o4 = fmaxf(fmaf(dv_self, acc[4], bb1.x), 0.f);
        float o5 = fmaxf(fmaf(dv_self, acc[5], bb1.y), 0.f);
        float o6 = fmaxf(fmaf(dv_self, acc[6], bb1.z), 0.f);
        float o7 = fmaxf(fmaf(dv_self, acc[7], bb1.w), 0.f);
        ushort4 s0 = make_ushort4(f2bf(o0), f2bf(o1), f2bf(o2), f2bf(o3));
        ushort4 s1 = make_ushort4(f2bf(o4), f2bf(o5), f2bf(o6), f2bf(o7));
        *(ushort4*)&As[lrow * KP + l16 * 8] = s0;
        *(ushort4*)&As[lrow * KP + l16 * 8 + 4] = s1;
    }
    __syncthreads();

    // ---- layer-2 GEMM: h2[64 x 64] = dinv * (As @ W2) ----
    const int w = t >> 6;
    const int lm = lane & 15;
    const int qd = lane >> 4;
    const int n0w = w * 16;

    f32x4 c4[4];
#pragma unroll
    for (int mi = 0; mi < 4; ++mi) c4[mi] = (f32x4){0.f, 0.f, 0.f, 0.f};

#pragma unroll
    for (int ks = 0; ks < 4; ++ks) {
        bf16x8 a[4], b;
#pragma unroll
        for (int mi = 0; mi < 4; ++mi)
            a[mi] = *(const bf16x8*)&As[(mi * 16 + lm) * KP + ks * 32 + qd * 8];
        b = *(const bf16x8*)&Bs[(n0w + lm) * KP + ks * 32 + qd * 8];
#pragma unroll
        for (int mi = 0; mi < 4; ++mi)
            c4[mi] = __builtin_amdgcn_mfma_f32_16x16x32_bf16(a[mi], b, c4[mi], 0, 0, 0);
    }

#pragma unroll
    for (int mi = 0; mi < 4; ++mi) {
        int col = n0w + lm;
#pragma unroll
        for (int r = 0; r < 4; ++r) {
            int lrow = mi * 16 + qd * 4 + r;
            int row = m0 + lrow;
            if (row < n) h2[(size_t)row * 64 + col] = f2bf(sDin[lrow] * c4[mi][r]);
        }
    }
}

// 64-feature layer: 8 nodes/wave, 8 lanes/node (rows are 128 B). fp32 output.
// 16-edge batches: 2 index loads + 16 row loads in flight.
__global__ __launch_bounds__(256) void k_gather64(const int* __restrict__ rp,
                                                  const int* __restrict__ deg,
                                                  const int* __restrict__ eperm,
                                                  const float* __restrict__ dinv,
                                                  const uint4* __restrict__ h4,  // bf16 rows: 8 uint4/row
                                                  const float* __restrict__ bias,
                                                  float* __restrict__ out, int n) {
    const int t = threadIdx.x;
    const int lane = t & 63;
    const int l8 = lane & 7;
    const int gbase = lane & 56;
    const int node = blockIdx.x * 32 + (t >> 6) * 8 + (lane >> 3);
    const bool valid = node < n;

    int beg = 0, end = 0;
    if (valid) {
        beg = rp[node];
        end = beg + deg[node];
    }

    float acc[8];
#pragma unroll
    for (int i = 0; i < 8; ++i) acc[i] = 0.f;
    if (valid) accum_row(acc, h4[(size_t)node * 8 + l8]);  // self

    int j = beg;
    // ---- full 16-edge batches ----
    for (; j + 16 <= end; j += 16) {
        int ep0 = eperm[j + l8];
        int ep1 = eperm[j + 8 + l8];
        int idx[16];
#pragma unroll
        for (int k = 0; k < 8; ++k) idx[k] = __shfl(ep0, gbase + k);
#pragma unroll
        for (int k = 0; k < 8; ++k) idx[8 + k] = __shfl(ep1, gbase + k);
        uint4 v[16];
#pragma unroll
        for (int k = 0; k < 16; ++k) v[k] = h4[(size_t)idx[k] * 8 + l8];
#pragma unroll
        for (int k = 0; k < 16; ++k) accum_row(acc, v[k]);
    }
    int cnt = end - j;
    // ---- one 8-edge batch if present ----
    if (cnt >= 8) {
        int ep = eperm[j + l8];
        int idx[8];
#pragma unroll
        for (int k = 0; k < 8; ++k) idx[k] = __shfl(ep, gbase + k);
        uint4 v[8];
#pragma unroll
        for (int k = 0; k < 8; ++k) v[k] = h4[(size_t)idx[k] * 8 + l8];
#pragma unroll
        for (int k = 0; k < 8; ++k) accum_row(acc, v[k]);
        j += 8;
        cnt -= 8;
    }
    // ---- remainder (< 8 edges) ----
    if (cnt > 0) {
        int ep = eperm[j + (l8 < cnt ? l8 : cnt - 1)];
        int k = 0;
        for (; k + 4 <= cnt; k += 4) {
            int i0 = __shfl(ep, gbase + k);
            int i1 = __shfl(ep, gbase + k + 1);
            int i2 = __shfl(ep, gbase + k + 2);
            int i3 = __shfl(ep, gbase + k + 3);
            uint4 v0 = h4[(size_t)i0 * 8 + l8];
            uint4 v1 = h4[(size_t)i1 * 8 + l8];
            uint4 v2 = h4[(size_t)i2 * 8 + l8];
            uint4 v3 = h4[(size_t)i3 * 8 + l8];
            accum_row(acc, v0);
            accum_row(acc, v1);
            accum_row(acc, v2);
            accum_row(acc, v3);
        }
        for (; k < cnt; ++k) {
            int i0 = __shfl(ep, gbase + k);
            uint4 v0 = h4[(size_t)i0 * 8 + l8];
            accum_row(acc, v0);
        }
    }

    if (valid) {
        float dv = dinv[node];
        float4 b0 = ((const float4*)bias)[l8 * 2];
        float4 b1 = ((const float4*)bias)[l8 * 2 + 1];
        float4 o0, o1;
        o0.x = dv * acc[0] + b0.x; o0.y = dv * acc[1] + b0.y;
        o0.z = dv * acc[2] + b0.z; o0.w = dv * acc[3] + b0.w;
        o1.x = dv * acc[4] + b1.x; o1.y = dv * acc[5] + b1.y;
        o1.z = dv * acc[6] + b1.z; o1.w = dv * acc[7] + b1.w;
        float4* orow = (float4*)(out + (size_t)node * 64);
        orow[l8 * 2] = o0;
        orow[l8 * 2 + 1] = o1;
    }
}

// ---------------- launch ----------------

extern "C" void kernel_launch(void* const* d_in, const int* in_sizes, int n_in,
                              void* d_out, int out_size, void* d_ws, size_t ws_size,
                              hipStream_t stream) {
    const float* x  = (const float*)d_in[0];
    const int*   ei = (const int*)d_in[1];
    const float* W1 = (const float*)d_in[2];
    const float* b1 = (const float*)d_in[3];
    const float* W2 = (const float*)d_in[4];
    const float* b2 = (const float*)d_in[5];
    float* out = (float*)d_out;

    const int N = in_sizes[0] / 128;
    const int E = in_sizes[1] / 2;
    const int* src = ei;
    const int* dst = ei + E;
    const int NB = (N + 511) >> BSHIFT;                          // coarse buckets (<= 256)
    const int cap = (E + NB - 1) / NB + ((E / NB) >> 2) + 1024;  // padded window (mean+25%+1024)

    char* ws = (char*)d_ws;
    size_t off = 0;
    auto carve = [&](size_t bytes) -> void* {
        void* p = ws + off;
        off = (off + bytes + 255) & ~(size_t)255;
        return p;
    };
    float* dinv = (float*)carve((size_t)N * 4);
    int*   rp   = (int*)carve((size_t)N * 4);
    int*   deg  = (int*)carve((size_t)N * 4);
    int*   bcur = (int*)carve(256 * 4);
    unsigned int* binned = (unsigned int*)carve((size_t)NB * cap * 4);  // packed (dlocal,src)
    int*   eperm = (int*)carve((size_t)NB * cap * 4);                   // src, bucket-windowed
    unsigned short* h  = (unsigned short*)carve((size_t)N * 128 * 2);   // bf16 h = x@W1 (unscaled)
    unsigned short* h2 = (unsigned short*)carve((size_t)N * 128 * 2);   // bf16 layer-2 GEMM out (64 cols)

    const int gMm = (N + 63) / 64;
    const int nbin = (E + BIN_CHUNK - 1) / BIN_CHUNK;

    // ---- CSR build overlapped with layer-1 GEMM ----
    hipMemsetAsync(bcur, 0, 256 * sizeof(int), stream);
    k_bin_gemm1<<<nbin + gMm, THREADS, 0, stream>>>(src, dst, bcur, binned, E, NB, cap,
                                                    x, W1, h, N, nbin);
    k_node_place<<<NB, THREADS, 0, stream>>>(binned, bcur, cap, rp, deg, dinv, eperm, N);

    // ---- layer-1 gather fused with layer-2 GEMM ----
    k_gather_gemm2<<<gMm, THREADS, 0, stream>>>(rp, deg, eperm, dinv, (const uint4*)h, b1, W2, h2, N);

    // ---- layer-2 gather ----
    k_gather64<<<(N + 31) / 32, THREADS, 0, stream>>>(rp, deg, eperm, dinv, (const uint4*)h2, b2, out, N);
}

// Round 5
// 266.687 us; speedup vs baseline: 1.1620x; 1.0312x over previous
//
#include <hip/hip_runtime.h>
#include <hip/hip_bf16.h>

#define THREADS 256
#define BSHIFT 9              // 512 nodes per coarse bucket; NB = ceil(N/512) <= 256
#define BIN_CHUNK 4096        // edges per k_bin block (16/thread)
#define KP 136                // padded LDS row stride (shorts); KP*2=272 B, 16B-aligned

typedef __attribute__((ext_vector_type(8))) short bf16x8;
typedef __attribute__((ext_vector_type(8))) unsigned short u16x8;
typedef __attribute__((ext_vector_type(4))) float f32x4;

// ---------------- helpers ----------------

__device__ inline unsigned short f2bf(float f) {  // round-to-nearest-even
    unsigned int u = __float_as_uint(f);
    unsigned int r = (u + 0x7fffu + ((u >> 16) & 1u)) >> 16;
    return (unsigned short)r;
}

__device__ inline float2 bf2_to_f2(unsigned int u) {  // low bf16 -> x, high bf16 -> y
    float2 r;
    r.x = __uint_as_float(u << 16);
    r.y = __uint_as_float(u & 0xffff0000u);
    return r;
}

__device__ inline void accum_row(float* acc, uint4 v) {
    float2 a = bf2_to_f2(v.x), b = bf2_to_f2(v.y), c = bf2_to_f2(v.z), d = bf2_to_f2(v.w);
    acc[0] += a.x; acc[1] += a.y; acc[2] += b.x; acc[3] += b.y;
    acc[4] += c.x; acc[5] += c.y; acc[6] += d.x; acc[7] += d.y;
}

__device__ inline void accum_row_scaled(float* acc, uint4 v, float s) {
    float2 a = bf2_to_f2(v.x), b = bf2_to_f2(v.y), c = bf2_to_f2(v.z), d = bf2_to_f2(v.w);
    acc[0] = fmaf(s, a.x, acc[0]); acc[1] = fmaf(s, a.y, acc[1]);
    acc[2] = fmaf(s, b.x, acc[2]); acc[3] = fmaf(s, b.y, acc[3]);
    acc[4] = fmaf(s, c.x, acc[4]); acc[5] = fmaf(s, c.y, acc[5]);
    acc[6] = fmaf(s, d.x, acc[6]); acc[7] = fmaf(s, d.y, acc[7]);
}

// build a B-fragment (bf16x8: 8 consecutive k) from row-major fp32 W[K x ldn]
__device__ inline bf16x8 load_bfrag(const float* __restrict__ W, int ldn, int k0, int col) {
    bf16x8 b;
#pragma unroll
    for (int i = 0; i < 8; ++i) b[i] = (short)f2bf(W[(size_t)(k0 + i) * ldn + col]);
    return b;
}

// ---------------- fused: edge binning (blocks [0,nbin)) + layer-1 GEMM (rest) ---------
// Bin role: edge record (dst_local:9 << 23) | src into padded bucket windows.
// GEMM role: h[M x 128](bf16) = x[M x 128] @ W1 (unscaled — dinv folded into the
// gather so this kernel is independent of the CSR build and overlaps it).
// LDS is As-only (17.4 KB); W1 B-fragments are built in registers from L2-hot
// global (64 KB, shared by all blocks) so the bin role isn't LDS-throttled.

__global__ __launch_bounds__(256) void k_bin_gemm1(const int* __restrict__ src,
                                                   const int* __restrict__ dst,
                                                   int* __restrict__ bcur,
                                                   unsigned int* __restrict__ binned,
                                                   int E, int NB, int cap,
                                                   const float* __restrict__ x,
                                                   const float* __restrict__ W1,
                                                   unsigned short* __restrict__ h,
                                                   int M, int nbin) {
    __shared__ __align__(16) short As[64 * KP];  // 17,408 B (bin role reuses first 2 KB)
    const int t = threadIdx.x;

    if ((int)blockIdx.x < nbin) {
        // ---------------- bin role ----------------
        int* bcnt = (int*)As;
        int* bres = bcnt + 256;
        bcnt[t] = 0;
        __syncthreads();
        int base = blockIdx.x * BIN_CHUNK;
        int sv[16], dv[16];
#pragma unroll
        for (int i = 0; i < 16; ++i) {
            int e = base + t + i * 256;
            if (e < E) {
                sv[i] = src[e];
                dv[i] = dst[e];
                atomicAdd(&bcnt[dv[i] >> BSHIFT], 1);
            } else {
                dv[i] = -1;
            }
        }
        __syncthreads();
        if (t < NB) {
            int old = bcnt[t] ? atomicAdd(&bcur[t], bcnt[t]) : 0;
            bres[t] = t * cap + old;
        }
        __syncthreads();
#pragma unroll
        for (int i = 0; i < 16; ++i) {
            if (dv[i] >= 0) {
                int b = dv[i] >> BSHIFT;
                int pos = atomicAdd(&bres[b], 1);
                if (pos < (b + 1) * cap)  // overflow guard (statistically never trips)
                    binned[pos] = ((unsigned int)(dv[i] & 511) << 23) | (unsigned int)sv[i];
            }
        }
        return;
    }

    // ---------------- GEMM role: 64-row tile of h = x @ W1 ----------------
    const int m0 = ((int)blockIdx.x - nbin) * 64;
    {
        int ar = t >> 5;
        int ac = (t & 31) * 4;
#pragma unroll
        for (int rb = 0; rb < 64; rb += 8) {
            int lrow = rb + ar;
            int row = m0 + lrow;
            ushort4 sv = make_ushort4(0, 0, 0, 0);
            if (row < M) {
                float4 v = *(const float4*)(x + (size_t)row * 128 + ac);
                sv.x = f2bf(v.x); sv.y = f2bf(v.y); sv.z = f2bf(v.z); sv.w = f2bf(v.w);
            }
            *(ushort4*)&As[lrow * KP + ac] = sv;
        }
    }
    __syncthreads();

    const int w = t >> 6;
    const int lane = t & 63;
    const int lm = lane & 15;
    const int qd = lane >> 4;
    const int n0w = w * 32;

    f32x4 acc[4][2];
#pragma unroll
    for (int mi = 0; mi < 4; ++mi)
#pragma unroll
        for (int ni = 0; ni < 2; ++ni) acc[mi][ni] = (f32x4){0.f, 0.f, 0.f, 0.f};

#pragma unroll
    for (int ks = 0; ks < 4; ++ks) {
        bf16x8 b0 = load_bfrag(W1, 128, ks * 32 + qd * 8, n0w + lm);
        bf16x8 b1 = load_bfrag(W1, 128, ks * 32 + qd * 8, n0w + 16 + lm);
#pragma unroll
        for (int mi = 0; mi < 4; ++mi) {
            bf16x8 a = *(const bf16x8*)&As[(mi * 16 + lm) * KP + ks * 32 + qd * 8];
            acc[mi][0] = __builtin_amdgcn_mfma_f32_16x16x32_bf16(a, b0, acc[mi][0], 0, 0, 0);
            acc[mi][1] = __builtin_amdgcn_mfma_f32_16x16x32_bf16(a, b1, acc[mi][1], 0, 0, 0);
        }
    }

#pragma unroll
    for (int mi = 0; mi < 4; ++mi) {
#pragma unroll
        for (int ni = 0; ni < 2; ++ni) {
            int col = n0w + ni * 16 + lm;
#pragma unroll
            for (int r = 0; r < 4; ++r) {
                int lrow = mi * 16 + qd * 4 + r;
                int row = m0 + lrow;
                if (row < M) h[(size_t)row * 128 + col] = f2bf(acc[mi][ni][r]);
            }
        }
    }
}

// per-bucket: histogram -> intra-bucket scan -> rp/deg/dinv, then place srcs
// into eperm via LDS cursors. One block per bucket; window re-read is L2-hot.
__global__ __launch_bounds__(256) void k_node_place(const unsigned int* __restrict__ binned,
                                                    const int* __restrict__ bcur, int cap,
                                                    int* __restrict__ rp,
                                                    int* __restrict__ deg,
                                                    float* __restrict__ dinv,
                                                    int* __restrict__ eperm, int N) {
    __shared__ int lc[512];
    __shared__ int s[256];
    int b = blockIdx.x;
    int t = threadIdx.x;
    int beg = b * cap;
    int end = beg + min(bcur[b], cap);
    int d0 = b << BSHIFT;
    lc[t] = 0;
    lc[t + 256] = 0;
    __syncthreads();
    for (int j = beg + t; j < end; j += 256) atomicAdd(&lc[binned[j] >> 23], 1);
    __syncthreads();
    int a = lc[2 * t], c = lc[2 * t + 1];
    int pair = a + c;
    s[t] = pair;
    __syncthreads();
    for (int off = 1; off < 256; off <<= 1) {
        int add = (t >= off) ? s[t - off] : 0;
        __syncthreads();
        s[t] += add;
        __syncthreads();
    }
    int excl = s[t] - pair;
    int st0 = beg + excl, st1 = st0 + a;
    int node0 = d0 + 2 * t;
    if (node0 < N) {
        rp[node0] = st0;
        deg[node0] = a;
        dinv[node0] = rsqrtf((float)a + 1.0f);  // +1 = self-loop
    }
    if (node0 + 1 < N) {
        rp[node0 + 1] = st1;
        deg[node0 + 1] = c;
        dinv[node0 + 1] = rsqrtf((float)c + 1.0f);
    }
    __syncthreads();
    lc[2 * t] = st0;               // repurpose lc as placement cursors
    lc[2 * t + 1] = st1;
    __syncthreads();
    for (int j = beg + t; j < end; j += 256) {
        unsigned int p = binned[j];
        int pos = atomicAdd(&lc[p >> 23], 1);
        eperm[pos] = (int)(p & 0x7fffffu);
    }
}

// ---------------- fused: layer-1 gather + layer-2 GEMM ----------------
// Block owns 64 nodes. Gather (4 rounds x 4 waves x 4 nodes): for node d,
// agg = sum_e dinv[src]*h[src] + dinv[d]*h[d]; row = relu(dinv[d]*agg + b1)
// -> bf16 -> LDS As[64][KP] (single aligned 16-B store: conflict-minimal).
// GEMM: h2 = dinv[row]*(As @ W2), W2 B-frags built in registers (L2-hot).
// LDS = 17.4 KB and __launch_bounds__(256,8) pins VGPR<=64 -> 8 blocks/CU so
// the fetch-throughput-capped gather keeps full miss concurrency.

__global__ __launch_bounds__(256, 8) void k_gather_gemm2(const int* __restrict__ rp,
                                                         const int* __restrict__ deg,
                                                         const int* __restrict__ eperm,
                                                         const float* __restrict__ dinv,
                                                         const uint4* __restrict__ h4,  // bf16 rows: 16 uint4
                                                         const float* __restrict__ b1,
                                                         const float* __restrict__ W2,
                                                         unsigned short* __restrict__ h2,  // bf16 [n x 64]
                                                         int n) {
    __shared__ __align__(16) short As[64 * KP];  // 17,408 B

    const int t = threadIdx.x;
    const int lane = t & 63;
    const int l16 = lane & 15;
    const int gbase = lane & 48;
    const int m0 = blockIdx.x * 64;

    // gather rounds: 4 waves x 4 lane-groups x 4 rounds = 64 nodes
#pragma unroll 1
    for (int r = 0; r < 4; ++r) {
        const int lrow = r * 16 + ((t >> 6) << 2) + (lane >> 4);
        const int node = m0 + lrow;
        const bool valid = node < n;

        int beg = 0, end = 0;
        float dv_self = 0.f;
        if (valid) {
            beg = rp[node];
            end = beg + deg[node];
            dv_self = dinv[node];
        }

        float acc[8];
#pragma unroll
        for (int i = 0; i < 8; ++i) acc[i] = 0.f;
        if (valid) accum_row_scaled(acc, h4[(size_t)node * 16 + l16], dv_self);  // self-loop

        for (int j = beg; j < end; j += 16) {
            int cnt = end - j;
            if (cnt > 16) cnt = 16;
            int ep = eperm[j + (l16 < cnt ? l16 : cnt - 1)];
            float dvv = dinv[ep];
            int k = 0;
            for (; k + 4 <= cnt; k += 4) {
                int i0 = __shfl(ep, gbase + k);
                int i1 = __shfl(ep, gbase + k + 1);
                int i2 = __shfl(ep, gbase + k + 2);
                int i3 = __shfl(ep, gbase + k + 3);
                float d0 = __shfl(dvv, gbase + k);
                float d1 = __shfl(dvv, gbase + k + 1);
                float d2 = __shfl(dvv, gbase + k + 2);
                float d3 = __shfl(dvv, gbase + k + 3);
                uint4 v0 = h4[(size_t)i0 * 16 + l16];
                uint4 v1 = h4[(size_t)i1 * 16 + l16];
                uint4 v2 = h4[(size_t)i2 * 16 + l16];
                uint4 v3 = h4[(size_t)i3 * 16 + l16];
                accum_row_scaled(acc, v0, d0);
                accum_row_scaled(acc, v1, d1);
                accum_row_scaled(acc, v2, d2);
                accum_row_scaled(acc, v3, d3);
            }
            for (; k < cnt; ++k) {
                int i0 = __shfl(ep, gbase + k);
                float d0 = __shfl(dvv, gbase + k);
                uint4 v0 = h4[(size_t)i0 * 16 + l16];
                accum_row_scaled(acc, v0, d0);
            }
        }

        // layer-1 epilogue: relu(dinv*agg + b1) -> bf16 -> one 16-B LDS store
        float4 bb0 = ((const float4*)b1)[l16 * 2];
        float4 bb1 = ((const float4*)b1)[l16 * 2 + 1];
        u16x8 s;
        s[0] = f2bf(fmaxf(fmaf(dv_self, acc[0], bb0.x), 0.f));
        s[1] = f2bf(fmaxf(fmaf(dv_self, acc[1], bb0.y), 0.f));
        s[2] = f2bf(fmaxf(fmaf(dv_self, acc[2], bb0.z), 0.f));
        s[3] = f2bf(fmaxf(fmaf(dv_self, acc[3], bb0.w), 0.f));
        s[4] = f2bf(fmaxf(fmaf(dv_self, acc[4], bb1.x), 0.f));
        s[5] = f2bf(fmaxf(fmaf(dv_self, acc[5], bb1.y), 0.f));
        s[6] = f2bf(fmaxf(fmaf(dv_self, acc[6], bb1.z), 0.f));
        s[7] = f2bf(fmaxf(fmaf(dv_self, acc[7], bb1.w), 0.f));
        *(u16x8*)&As[lrow * KP + l16 * 8] = s;  // 272-B row stride, 16-B aligned
    }
    __syncthreads();
    __builtin_amdgcn_sched_barrier(0);  // keep W2 frag loads out of the gather phase

    // ---- layer-2 GEMM: h2[64 x 64] = dinv * (As @ W2) ----
    const int w = t >> 6;
    const int lm = lane & 15;
    const int qd = lane >> 4;
    const int n0w = w * 16;
    const int col = n0w + lm;

    f32x4 c4[4];
#pragma unroll
    for (int mi = 0; mi < 4; ++mi) c4[mi] = (f32x4){0.f, 0.f, 0.f, 0.f};

#pragma unroll
    for (int ks = 0; ks < 4; ++ks) {
        bf16x8 b = load_bfrag(W2, 64, ks * 32 + qd * 8, col);
#pragma unroll
        for (int mi = 0; mi < 4; ++mi) {
            bf16x8 a = *(const bf16x8*)&As[(mi * 16 + lm) * KP + ks * 32 + qd * 8];
            c4[mi] = __builtin_amdgcn_mfma_f32_16x16x32_bf16(a, b, c4[mi], 0, 0, 0);
        }
    }

#pragma unroll
    for (int mi = 0; mi < 4; ++mi) {
#pragma unroll
        for (int r = 0; r < 4; ++r) {
            int lrow = mi * 16 + qd * 4 + r;
            int row = m0 + lrow;
            if (row < n) h2[(size_t)row * 64 + col] = f2bf(dinv[row] * c4[mi][r]);
        }
    }
}

// 64-feature layer: 8 nodes/wave, 8 lanes/node (rows are 128 B). fp32 output.
// 16-edge batches: 2 index loads + 16 row loads in flight.
__global__ __launch_bounds__(256) void k_gather64(const int* __restrict__ rp,
                                                  const int* __restrict__ deg,
                                                  const int* __restrict__ eperm,
                                                  const float* __restrict__ dinv,
                                                  const uint4* __restrict__ h4,  // bf16 rows: 8 uint4/row
                                                  const float* __restrict__ bias,
                                                  float* __restrict__ out, int n) {
    const int t = threadIdx.x;
    const int lane = t & 63;
    const int l8 = lane & 7;
    const int gbase = lane & 56;
    const int node = blockIdx.x * 32 + (t >> 6) * 8 + (lane >> 3);
    const bool valid = node < n;

    int beg = 0, end = 0;
    if (valid) {
        beg = rp[node];
        end = beg + deg[node];
    }

    float acc[8];
#pragma unroll
    for (int i = 0; i < 8; ++i) acc[i] = 0.f;
    if (valid) accum_row(acc, h4[(size_t)node * 8 + l8]);  // self

    int j = beg;
    // ---- full 16-edge batches ----
    for (; j + 16 <= end; j += 16) {
        int ep0 = eperm[j + l8];
        int ep1 = eperm[j + 8 + l8];
        int idx[16];
#pragma unroll
        for (int k = 0; k < 8; ++k) idx[k] = __shfl(ep0, gbase + k);
#pragma unroll
        for (int k = 0; k < 8; ++k) idx[8 + k] = __shfl(ep1, gbase + k);
        uint4 v[16];
#pragma unroll
        for (int k = 0; k < 16; ++k) v[k] = h4[(size_t)idx[k] * 8 + l8];
#pragma unroll
        for (int k = 0; k < 16; ++k) accum_row(acc, v[k]);
    }
    int cnt = end - j;
    // ---- one 8-edge batch if present ----
    if (cnt >= 8) {
        int ep = eperm[j + l8];
        int idx[8];
#pragma unroll
        for (int k = 0; k < 8; ++k) idx[k] = __shfl(ep, gbase + k);
        uint4 v[8];
#pragma unroll
        for (int k = 0; k < 8; ++k) v[k] = h4[(size_t)idx[k] * 8 + l8];
#pragma unroll
        for (int k = 0; k < 8; ++k) accum_row(acc, v[k]);
        j += 8;
        cnt -= 8;
    }
    // ---- remainder (< 8 edges) ----
    if (cnt > 0) {
        int ep = eperm[j + (l8 < cnt ? l8 : cnt - 1)];
        int k = 0;
        for (; k + 4 <= cnt; k += 4) {
            int i0 = __shfl(ep, gbase + k);
            int i1 = __shfl(ep, gbase + k + 1);
            int i2 = __shfl(ep, gbase + k + 2);
            int i3 = __shfl(ep, gbase + k + 3);
            uint4 v0 = h4[(size_t)i0 * 8 + l8];
            uint4 v1 = h4[(size_t)i1 * 8 + l8];
            uint4 v2 = h4[(size_t)i2 * 8 + l8];
            uint4 v3 = h4[(size_t)i3 * 8 + l8];
            accum_row(acc, v0);
            accum_row(acc, v1);
            accum_row(acc, v2);
            accum_row(acc, v3);
        }
        for (; k < cnt; ++k) {
            int i0 = __shfl(ep, gbase + k);
            uint4 v0 = h4[(size_t)i0 * 8 + l8];
            accum_row(acc, v0);
        }
    }

    if (valid) {
        float dv = dinv[node];
        float4 b0 = ((const float4*)bias)[l8 * 2];
        float4 b1 = ((const float4*)bias)[l8 * 2 + 1];
        float4 o0, o1;
        o0.x = dv * acc[0] + b0.x; o0.y = dv * acc[1] + b0.y;
        o0.z = dv * acc[2] + b0.z; o0.w = dv * acc[3] + b0.w;
        o1.x = dv * acc[4] + b1.x; o1.y = dv * acc[5] + b1.y;
        o1.z = dv * acc[6] + b1.z; o1.w = dv * acc[7] + b1.w;
        float4* orow = (float4*)(out + (size_t)node * 64);
        orow[l8 * 2] = o0;
        orow[l8 * 2 + 1] = o1;
    }
}

// ---------------- launch ----------------

extern "C" void kernel_launch(void* const* d_in, const int* in_sizes, int n_in,
                              void* d_out, int out_size, void* d_ws, size_t ws_size,
                              hipStream_t stream) {
    const float* x  = (const float*)d_in[0];
    const int*   ei = (const int*)d_in[1];
    const float* W1 = (const float*)d_in[2];
    const float* b1 = (const float*)d_in[3];
    const float* W2 = (const float*)d_in[4];
    const float* b2 = (const float*)d_in[5];
    float* out = (float*)d_out;

    const int N = in_sizes[0] / 128;
    const int E = in_sizes[1] / 2;
    const int* src = ei;
    const int* dst = ei + E;
    const int NB = (N + 511) >> BSHIFT;                          // coarse buckets (<= 256)
    const int cap = (E + NB - 1) / NB + ((E / NB) >> 2) + 1024;  // padded window (mean+25%+1024)

    char* ws = (char*)d_ws;
    size_t off = 0;
    auto carve = [&](size_t bytes) -> void* {
        void* p = ws + off;
        off = (off + bytes + 255) & ~(size_t)255;
        return p;
    };
    float* dinv = (float*)carve((size_t)N * 4);
    int*   rp   = (int*)carve((size_t)N * 4);
    int*   deg  = (int*)carve((size_t)N * 4);
    int*   bcur = (int*)carve(256 * 4);
    unsigned int* binned = (unsigned int*)carve((size_t)NB * cap * 4);  // packed (dlocal,src)
    int*   eperm = (int*)carve((size_t)NB * cap * 4);                   // src, bucket-windowed
    unsigned short* h  = (unsigned short*)carve((size_t)N * 128 * 2);   // bf16 h = x@W1 (unscaled)
    unsigned short* h2 = (unsigned short*)carve((size_t)N * 128 * 2);   // bf16 layer-2 GEMM out (64 cols)

    const int gMm = (N + 63) / 64;
    const int nbin = (E + BIN_CHUNK - 1) / BIN_CHUNK;

    // ---- CSR build overlapped with layer-1 GEMM ----
    hipMemsetAsync(bcur, 0, 256 * sizeof(int), stream);
    k_bin_gemm1<<<nbin + gMm, THREADS, 0, stream>>>(src, dst, bcur, binned, E, NB, cap,
                                                    x, W1, h, N, nbin);
    k_node_place<<<NB, THREADS, 0, stream>>>(binned, bcur, cap, rp, deg, dinv, eperm, N);

    // ---- layer-1 gather fused with layer-2 GEMM ----
    k_gather_gemm2<<<gMm, THREADS, 0, stream>>>(rp, deg, eperm, dinv, (const uint4*)h, b1, W2, h2, N);

    // ---- layer-2 gather ----
    k_gather64<<<(N + 31) / 32, THREADS, 0, stream>>>(rp, deg, eperm, dinv, (const uint4*)h2, b2, out, N);
}

// Round 6
// 257.952 us; speedup vs baseline: 1.2014x; 1.0339x over previous
//
#include <hip/hip_runtime.h>
#include <hip/hip_bf16.h>

#define THREADS 256
#define BSHIFT 9              // 512 nodes per coarse bucket; NB = ceil(N/512) <= 256
#define BIN_CHUNK 4096        // edges per k_bin block (16/thread)
#define KP 136                // padded LDS row stride (shorts); KP*2=272 B, 16B-aligned

typedef __attribute__((ext_vector_type(8))) short bf16x8;
typedef __attribute__((ext_vector_type(8))) unsigned short u16x8;
typedef __attribute__((ext_vector_type(4))) float f32x4;

// ---------------- helpers ----------------

__device__ inline unsigned short f2bf(float f) {  // round-to-nearest-even
    unsigned int u = __float_as_uint(f);
    unsigned int r = (u + 0x7fffu + ((u >> 16) & 1u)) >> 16;
    return (unsigned short)r;
}

__device__ inline float2 bf2_to_f2(unsigned int u) {  // low bf16 -> x, high bf16 -> y
    float2 r;
    r.x = __uint_as_float(u << 16);
    r.y = __uint_as_float(u & 0xffff0000u);
    return r;
}

__device__ inline void accum_row(float* acc, uint4 v) {
    float2 a = bf2_to_f2(v.x), b = bf2_to_f2(v.y), c = bf2_to_f2(v.z), d = bf2_to_f2(v.w);
    acc[0] += a.x; acc[1] += a.y; acc[2] += b.x; acc[3] += b.y;
    acc[4] += c.x; acc[5] += c.y; acc[6] += d.x; acc[7] += d.y;
}

__device__ inline void accum_row_scaled(float* acc, uint4 v, float s) {
    float2 a = bf2_to_f2(v.x), b = bf2_to_f2(v.y), c = bf2_to_f2(v.z), d = bf2_to_f2(v.w);
    acc[0] = fmaf(s, a.x, acc[0]); acc[1] = fmaf(s, a.y, acc[1]);
    acc[2] = fmaf(s, b.x, acc[2]); acc[3] = fmaf(s, b.y, acc[3]);
    acc[4] = fmaf(s, c.x, acc[4]); acc[5] = fmaf(s, c.y, acc[5]);
    acc[6] = fmaf(s, d.x, acc[6]); acc[7] = fmaf(s, d.y, acc[7]);
}

// build a B-fragment (bf16x8: 8 consecutive k) from row-major fp32 W[K x ldn]
__device__ inline bf16x8 load_bfrag(const float* __restrict__ W, int ldn, int k0, int col) {
    bf16x8 b;
#pragma unroll
    for (int i = 0; i < 8; ++i) b[i] = (short)f2bf(W[(size_t)(k0 + i) * ldn + col]);
    return b;
}

// ---------------- fused: edge binning (blocks [0,nbin)) + layer-1 GEMM (rest) ---------
// Bin role: edge record (dst_local:9 << 23) | src into padded bucket windows.
// GEMM role: h[M x 128](bf16) = x[M x 128] @ W1 (unscaled — dinv folded into the
// gather so this kernel is independent of the CSR build and overlaps it).

__global__ __launch_bounds__(256) void k_bin_gemm1(const int* __restrict__ src,
                                                   const int* __restrict__ dst,
                                                   int* __restrict__ bcur,
                                                   unsigned int* __restrict__ binned,
                                                   int E, int NB, int cap,
                                                   const float* __restrict__ x,
                                                   const float* __restrict__ W1,
                                                   unsigned short* __restrict__ h,
                                                   int M, int nbin) {
    __shared__ __align__(16) short As[64 * KP];  // 17,408 B (bin role reuses first 2 KB)
    const int t = threadIdx.x;

    if ((int)blockIdx.x < nbin) {
        // ---------------- bin role ----------------
        int* bcnt = (int*)As;
        int* bres = bcnt + 256;
        bcnt[t] = 0;
        __syncthreads();
        int base = blockIdx.x * BIN_CHUNK;
        int sv[16], dv[16];
#pragma unroll
        for (int i = 0; i < 16; ++i) {
            int e = base + t + i * 256;
            if (e < E) {
                sv[i] = src[e];
                dv[i] = dst[e];
                atomicAdd(&bcnt[dv[i] >> BSHIFT], 1);
            } else {
                dv[i] = -1;
            }
        }
        __syncthreads();
        if (t < NB) {
            int old = bcnt[t] ? atomicAdd(&bcur[t], bcnt[t]) : 0;
            bres[t] = t * cap + old;
        }
        __syncthreads();
#pragma unroll
        for (int i = 0; i < 16; ++i) {
            if (dv[i] >= 0) {
                int b = dv[i] >> BSHIFT;
                int pos = atomicAdd(&bres[b], 1);
                if (pos < (b + 1) * cap)  // overflow guard (statistically never trips)
                    binned[pos] = ((unsigned int)(dv[i] & 511) << 23) | (unsigned int)sv[i];
            }
        }
        return;
    }

    // ---------------- GEMM role: 64-row tile of h = x @ W1 ----------------
    const int m0 = ((int)blockIdx.x - nbin) * 64;
    {
        int ar = t >> 5;
        int ac = (t & 31) * 4;
#pragma unroll
        for (int rb = 0; rb < 64; rb += 8) {
            int lrow = rb + ar;
            int row = m0 + lrow;
            ushort4 sv = make_ushort4(0, 0, 0, 0);
            if (row < M) {
                float4 v = *(const float4*)(x + (size_t)row * 128 + ac);
                sv.x = f2bf(v.x); sv.y = f2bf(v.y); sv.z = f2bf(v.z); sv.w = f2bf(v.w);
            }
            *(ushort4*)&As[lrow * KP + ac] = sv;
        }
    }
    __syncthreads();

    const int w = t >> 6;
    const int lane = t & 63;
    const int lm = lane & 15;
    const int qd = lane >> 4;
    const int n0w = w * 32;

    f32x4 acc[4][2];
#pragma unroll
    for (int mi = 0; mi < 4; ++mi)
#pragma unroll
        for (int ni = 0; ni < 2; ++ni) acc[mi][ni] = (f32x4){0.f, 0.f, 0.f, 0.f};

#pragma unroll
    for (int ks = 0; ks < 4; ++ks) {
        bf16x8 b0 = load_bfrag(W1, 128, ks * 32 + qd * 8, n0w + lm);
        bf16x8 b1 = load_bfrag(W1, 128, ks * 32 + qd * 8, n0w + 16 + lm);
#pragma unroll
        for (int mi = 0; mi < 4; ++mi) {
            bf16x8 a = *(const bf16x8*)&As[(mi * 16 + lm) * KP + ks * 32 + qd * 8];
            acc[mi][0] = __builtin_amdgcn_mfma_f32_16x16x32_bf16(a, b0, acc[mi][0], 0, 0, 0);
            acc[mi][1] = __builtin_amdgcn_mfma_f32_16x16x32_bf16(a, b1, acc[mi][1], 0, 0, 0);
        }
    }

#pragma unroll
    for (int mi = 0; mi < 4; ++mi) {
#pragma unroll
        for (int ni = 0; ni < 2; ++ni) {
            int col = n0w + ni * 16 + lm;
#pragma unroll
            for (int r = 0; r < 4; ++r) {
                int lrow = mi * 16 + qd * 4 + r;
                int row = m0 + lrow;
                if (row < M) h[(size_t)row * 128 + col] = f2bf(acc[mi][ni][r]);
            }
        }
    }
}

// per-bucket: histogram -> intra-bucket scan -> rp/deg/dinv, then place srcs
// into eperm via LDS cursors. Extra block (blockIdx == NB) converts W2 to
// transposed bf16 W2t[64][128] so the fused gather's GEMM tail can load
// B-fragments as single dwordx4 (L2-hot).
__global__ __launch_bounds__(256) void k_node_place(const unsigned int* __restrict__ binned,
                                                    const int* __restrict__ bcur, int cap,
                                                    int* __restrict__ rp,
                                                    int* __restrict__ deg,
                                                    float* __restrict__ dinv,
                                                    int* __restrict__ eperm, int N,
                                                    const float* __restrict__ W2,
                                                    unsigned short* __restrict__ W2t, int NB) {
    int b = blockIdx.x;
    int t = threadIdx.x;
    if (b == NB) {  // W2[128 x 64] fp32 -> W2t[64 x 128] bf16
        for (int i = t; i < 64 * 128; i += 256) {
            int nn = i >> 7;
            int kk = i & 127;
            W2t[i] = f2bf(W2[(size_t)kk * 64 + nn]);
        }
        return;
    }
    __shared__ int lc[512];
    __shared__ int s[256];
    int beg = b * cap;
    int end = beg + min(bcur[b], cap);
    int d0 = b << BSHIFT;
    lc[t] = 0;
    lc[t + 256] = 0;
    __syncthreads();
    for (int j = beg + t; j < end; j += 256) atomicAdd(&lc[binned[j] >> 23], 1);
    __syncthreads();
    int a = lc[2 * t], c = lc[2 * t + 1];
    int pair = a + c;
    s[t] = pair;
    __syncthreads();
    for (int off = 1; off < 256; off <<= 1) {
        int add = (t >= off) ? s[t - off] : 0;
        __syncthreads();
        s[t] += add;
        __syncthreads();
    }
    int excl = s[t] - pair;
    int st0 = beg + excl, st1 = st0 + a;
    int node0 = d0 + 2 * t;
    if (node0 < N) {
        rp[node0] = st0;
        deg[node0] = a;
        dinv[node0] = rsqrtf((float)a + 1.0f);  // +1 = self-loop
    }
    if (node0 + 1 < N) {
        rp[node0 + 1] = st1;
        deg[node0 + 1] = c;
        dinv[node0 + 1] = rsqrtf((float)c + 1.0f);
    }
    __syncthreads();
    lc[2 * t] = st0;               // repurpose lc as placement cursors
    lc[2 * t + 1] = st1;
    __syncthreads();
    for (int j = beg + t; j < end; j += 256) {
        unsigned int p = binned[j];
        int pos = atomicAdd(&lc[p >> 23], 1);
        eperm[pos] = (int)(p & 0x7fffffu);
    }
}

// ---------------- fused: layer-1 gather + layer-2 GEMM (16-node blocks) ----------------
// R2's measured-best gather geometry (16 nodes/block, 4 nodes/wave, 16 lanes/node,
// one round) + a tiny 16x64 MFMA tail. agg = sum_e dinv[src]*h[src] + dinv[d]*h[d];
// As row = relu(dinv[d]*agg + b1) (bf16, LDS); h2 = dinv[row]*(As @ W2) via W2t
// bf16 B-frags (single dwordx4, L2-hot). LDS 4.4 KB; no forced VGPR bound.

__global__ __launch_bounds__(256) void k_gather_gemm2(const int* __restrict__ rp,
                                                      const int* __restrict__ deg,
                                                      const int* __restrict__ eperm,
                                                      const float* __restrict__ dinv,
                                                      const uint4* __restrict__ h4,  // bf16 rows: 16 uint4
                                                      const float* __restrict__ b1,
                                                      const unsigned short* __restrict__ W2t,  // bf16 [64][128]
                                                      unsigned short* __restrict__ h2,  // bf16 [n x 64]
                                                      int n) {
    __shared__ __align__(16) short As[16 * KP];  // 4,352 B

    const int t = threadIdx.x;
    const int lane = t & 63;
    const int l16 = lane & 15;
    const int gbase = lane & 48;
    const int m0 = blockIdx.x * 16;
    const int lrow = (t >> 6) * 4 + (lane >> 4);
    const int node = m0 + lrow;
    const bool valid = node < n;

    int beg = 0, end = 0;
    float dv_self = 0.f;
    if (valid) {
        beg = rp[node];
        end = beg + deg[node];
        dv_self = dinv[node];
    }

    float acc[8];
#pragma unroll
    for (int i = 0; i < 8; ++i) acc[i] = 0.f;
    if (valid) accum_row_scaled(acc, h4[(size_t)node * 16 + l16], dv_self);  // self-loop

    for (int j = beg; j < end; j += 16) {
        int cnt = end - j;
        if (cnt > 16) cnt = 16;
        int ep = eperm[j + (l16 < cnt ? l16 : cnt - 1)];
        float dvv = dinv[ep];
        int k = 0;
        for (; k + 4 <= cnt; k += 4) {
            int i0 = __shfl(ep, gbase + k);
            int i1 = __shfl(ep, gbase + k + 1);
            int i2 = __shfl(ep, gbase + k + 2);
            int i3 = __shfl(ep, gbase + k + 3);
            float d0 = __shfl(dvv, gbase + k);
            float d1 = __shfl(dvv, gbase + k + 1);
            float d2 = __shfl(dvv, gbase + k + 2);
            float d3 = __shfl(dvv, gbase + k + 3);
            uint4 v0 = h4[(size_t)i0 * 16 + l16];
            uint4 v1 = h4[(size_t)i1 * 16 + l16];
            uint4 v2 = h4[(size_t)i2 * 16 + l16];
            uint4 v3 = h4[(size_t)i3 * 16 + l16];
            accum_row_scaled(acc, v0, d0);
            accum_row_scaled(acc, v1, d1);
            accum_row_scaled(acc, v2, d2);
            accum_row_scaled(acc, v3, d3);
        }
        for (; k < cnt; ++k) {
            int i0 = __shfl(ep, gbase + k);
            float d0 = __shfl(dvv, gbase + k);
            uint4 v0 = h4[(size_t)i0 * 16 + l16];
            accum_row_scaled(acc, v0, d0);
        }
    }

    // layer-1 epilogue: relu(dinv*agg + b1) -> bf16 -> one 16-B LDS store
    {
        float4 bb0 = ((const float4*)b1)[l16 * 2];
        float4 bb1 = ((const float4*)b1)[l16 * 2 + 1];
        u16x8 s;
        s[0] = f2bf(fmaxf(fmaf(dv_self, acc[0], bb0.x), 0.f));
        s[1] = f2bf(fmaxf(fmaf(dv_self, acc[1], bb0.y), 0.f));
        s[2] = f2bf(fmaxf(fmaf(dv_self, acc[2], bb0.z), 0.f));
        s[3] = f2bf(fmaxf(fmaf(dv_self, acc[3], bb0.w), 0.f));
        s[4] = f2bf(fmaxf(fmaf(dv_self, acc[4], bb1.x), 0.f));
        s[5] = f2bf(fmaxf(fmaf(dv_self, acc[5], bb1.y), 0.f));
        s[6] = f2bf(fmaxf(fmaf(dv_self, acc[6], bb1.z), 0.f));
        s[7] = f2bf(fmaxf(fmaf(dv_self, acc[7], bb1.w), 0.f));
        *(u16x8*)&As[lrow * KP + l16 * 8] = s;  // 272-B row stride, 16-B aligned
    }
    __syncthreads();

    // ---- layer-2 GEMM tail: h2[16 x 64] = dinv * (As @ W2) ----
    const int w = t >> 6;
    const int lm = lane & 15;
    const int qd = lane >> 4;
    const int col = w * 16 + lm;

    f32x4 c4 = (f32x4){0.f, 0.f, 0.f, 0.f};
#pragma unroll
    for (int ks = 0; ks < 4; ++ks) {
        bf16x8 b = *(const bf16x8*)&W2t[(size_t)col * 128 + ks * 32 + qd * 8];
        bf16x8 a = *(const bf16x8*)&As[lm * KP + ks * 32 + qd * 8];
        c4 = __builtin_amdgcn_mfma_f32_16x16x32_bf16(a, b, c4, 0, 0, 0);
    }

#pragma unroll
    for (int r = 0; r < 4; ++r) {
        int row = m0 + qd * 4 + r;
        if (row < n) h2[(size_t)row * 64 + col] = f2bf(dinv[row] * c4[r]);
    }
}

// 64-feature layer: 8 nodes/wave, 8 lanes/node (rows are 128 B). fp32 output.
// 16-edge batches: 2 index loads + 16 row loads in flight.
__global__ __launch_bounds__(256) void k_gather64(const int* __restrict__ rp,
                                                  const int* __restrict__ deg,
                                                  const int* __restrict__ eperm,
                                                  const float* __restrict__ dinv,
                                                  const uint4* __restrict__ h4,  // bf16 rows: 8 uint4/row
                                                  const float* __restrict__ bias,
                                                  float* __restrict__ out, int n) {
    const int t = threadIdx.x;
    const int lane = t & 63;
    const int l8 = lane & 7;
    const int gbase = lane & 56;
    const int node = blockIdx.x * 32 + (t >> 6) * 8 + (lane >> 3);
    const bool valid = node < n;

    int beg = 0, end = 0;
    if (valid) {
        beg = rp[node];
        end = beg + deg[node];
    }

    float acc[8];
#pragma unroll
    for (int i = 0; i < 8; ++i) acc[i] = 0.f;
    if (valid) accum_row(acc, h4[(size_t)node * 8 + l8]);  // self

    int j = beg;
    // ---- full 16-edge batches ----
    for (; j + 16 <= end; j += 16) {
        int ep0 = eperm[j + l8];
        int ep1 = eperm[j + 8 + l8];
        int idx[16];
#pragma unroll
        for (int k = 0; k < 8; ++k) idx[k] = __shfl(ep0, gbase + k);
#pragma unroll
        for (int k = 0; k < 8; ++k) idx[8 + k] = __shfl(ep1, gbase + k);
        uint4 v[16];
#pragma unroll
        for (int k = 0; k < 16; ++k) v[k] = h4[(size_t)idx[k] * 8 + l8];
#pragma unroll
        for (int k = 0; k < 16; ++k) accum_row(acc, v[k]);
    }
    int cnt = end - j;
    // ---- one 8-edge batch if present ----
    if (cnt >= 8) {
        int ep = eperm[j + l8];
        int idx[8];
#pragma unroll
        for (int k = 0; k < 8; ++k) idx[k] = __shfl(ep, gbase + k);
        uint4 v[8];
#pragma unroll
        for (int k = 0; k < 8; ++k) v[k] = h4[(size_t)idx[k] * 8 + l8];
#pragma unroll
        for (int k = 0; k < 8; ++k) accum_row(acc, v[k]);
        j += 8;
        cnt -= 8;
    }
    // ---- remainder (< 8 edges) ----
    if (cnt > 0) {
        int ep = eperm[j + (l8 < cnt ? l8 : cnt - 1)];
        int k = 0;
        for (; k + 4 <= cnt; k += 4) {
            int i0 = __shfl(ep, gbase + k);
            int i1 = __shfl(ep, gbase + k + 1);
            int i2 = __shfl(ep, gbase + k + 2);
            int i3 = __shfl(ep, gbase + k + 3);
            uint4 v0 = h4[(size_t)i0 * 8 + l8];
            uint4 v1 = h4[(size_t)i1 * 8 + l8];
            uint4 v2 = h4[(size_t)i2 * 8 + l8];
            uint4 v3 = h4[(size_t)i3 * 8 + l8];
            accum_row(acc, v0);
            accum_row(acc, v1);
            accum_row(acc, v2);
            accum_row(acc, v3);
        }
        for (; k < cnt; ++k) {
            int i0 = __shfl(ep, gbase + k);
            uint4 v0 = h4[(size_t)i0 * 8 + l8];
            accum_row(acc, v0);
        }
    }

    if (valid) {
        float dv = dinv[node];
        float4 b0 = ((const float4*)bias)[l8 * 2];
        float4 b1 = ((const float4*)bias)[l8 * 2 + 1];
        float4 o0, o1;
        o0.x = dv * acc[0] + b0.x; o0.y = dv * acc[1] + b0.y;
        o0.z = dv * acc[2] + b0.z; o0.w = dv * acc[3] + b0.w;
        o1.x = dv * acc[4] + b1.x; o1.y = dv * acc[5] + b1.y;
        o1.z = dv * acc[6] + b1.z; o1.w = dv * acc[7] + b1.w;
        float4* orow = (float4*)(out + (size_t)node * 64);
        orow[l8 * 2] = o0;
        orow[l8 * 2 + 1] = o1;
    }
}

// ---------------- launch ----------------

extern "C" void kernel_launch(void* const* d_in, const int* in_sizes, int n_in,
                              void* d_out, int out_size, void* d_ws, size_t ws_size,
                              hipStream_t stream) {
    const float* x  = (const float*)d_in[0];
    const int*   ei = (const int*)d_in[1];
    const float* W1 = (const float*)d_in[2];
    const float* b1 = (const float*)d_in[3];
    const float* W2 = (const float*)d_in[4];
    const float* b2 = (const float*)d_in[5];
    float* out = (float*)d_out;

    const int N = in_sizes[0] / 128;
    const int E = in_sizes[1] / 2;
    const int* src = ei;
    const int* dst = ei + E;
    const int NB = (N + 511) >> BSHIFT;                          // coarse buckets (<= 256)
    const int cap = (E + NB - 1) / NB + ((E / NB) >> 2) + 1024;  // padded window (mean+25%+1024)

    char* ws = (char*)d_ws;
    size_t off = 0;
    auto carve = [&](size_t bytes) -> void* {
        void* p = ws + off;
        off = (off + bytes + 255) & ~(size_t)255;
        return p;
    };
    float* dinv = (float*)carve((size_t)N * 4);
    int*   rp   = (int*)carve((size_t)N * 4);
    int*   deg  = (int*)carve((size_t)N * 4);
    int*   bcur = (int*)carve(256 * 4);
    unsigned int* binned = (unsigned int*)carve((size_t)NB * cap * 4);  // packed (dlocal,src)
    int*   eperm = (int*)carve((size_t)NB * cap * 4);                   // src, bucket-windowed
    unsigned short* h   = (unsigned short*)carve((size_t)N * 128 * 2);  // bf16 h = x@W1 (unscaled)
    unsigned short* h2  = (unsigned short*)carve((size_t)N * 64 * 2);   // bf16 layer-2 GEMM out
    unsigned short* W2t = (unsigned short*)carve(64 * 128 * 2);         // bf16 W2 transposed

    const int gMm = (N + 63) / 64;
    const int nbin = (E + BIN_CHUNK - 1) / BIN_CHUNK;

    // ---- CSR build overlapped with layer-1 GEMM ----
    hipMemsetAsync(bcur, 0, 256 * sizeof(int), stream);
    k_bin_gemm1<<<nbin + gMm, THREADS, 0, stream>>>(src, dst, bcur, binned, E, NB, cap,
                                                    x, W1, h, N, nbin);
    k_node_place<<<NB + 1, THREADS, 0, stream>>>(binned, bcur, cap, rp, deg, dinv, eperm, N,
                                                 W2, W2t, NB);

    // ---- layer-1 gather fused with layer-2 GEMM (16-node blocks) ----
    k_gather_gemm2<<<(N + 15) / 16, THREADS, 0, stream>>>(rp, deg, eperm, dinv, (const uint4*)h,
                                                          b1, W2t, h2, N);

    // ---- layer-2 gather ----
    k_gather64<<<(N + 31) / 32, THREADS, 0, stream>>>(rp, deg, eperm, dinv, (const uint4*)h2, b2, out, N);
}